// Round 5
// baseline (505.581 us; speedup 1.0000x reference)
//
#include <hip/hip_runtime.h>
#include <math.h>

// ---------------------------------------------------------------------------
// UDTransNet fused forward. fp16 MFMA everywhere (fp32 accum), fp16
// intermediates, transposed weights, swizzled LDS, barrier-free flash attn.
// Sizes: B=4, N=576, E=256, C=4E=1024, H=8, dh=32, M=4N=2304.
// ---------------------------------------------------------------------------

namespace {
constexpr int Bq  = 4;
constexpr int Nn  = 576;
constexpr int Ee  = 256;
constexpr int Cc  = 1024;
constexpr int Mm  = 2304;
constexpr long BNE = (long)Bq * Nn * Ee;     // 589824
constexpr long CCl = (long)Cc * Cc;          // 1048576
constexpr float EPSV = 1e-3f;
constexpr float LOG2E = 1.4426950408889634f;
} // namespace

typedef _Float16 h16;
typedef _Float16 h8v __attribute__((ext_vector_type(8)));
typedef _Float16 h4v __attribute__((ext_vector_type(4)));
typedef float    f4v __attribute__((ext_vector_type(4)));

// ---------------------------------------------------------------------------
// wtrans: one dispatch converting everything.
//  blocks [0,928): 64x64 tiled transpose fp32[K][N] -> h16[N][K] of the 13
//  weight matrices (Wc parts 0-2: 256 tiles each; Wk,Wv,Wq0-3,Wo0-3: 16 each).
//  blocks [928,3232): straight fp32->fp16 copy of emb_C.
//  LDS transpose uses pitch-64 chunk-XOR swizzle: col = (chunk^((n>>3)&7))*8.
// ---------------------------------------------------------------------------
struct WtP {
  const float* src[13]; h16* dst[13];
  const float* embC; h16* dEmbC;
};

__global__ __launch_bounds__(256) void wtrans(WtP p)
{
  const int bt = blockIdx.x;
  const int t = threadIdx.x;
  if (bt >= 928) {
    const long i4 = ((long)(bt - 928) * 256 + t) * 4;
    const float4 v = *(const float4*)(p.embC + i4);
    h4v o = {(h16)v.x, (h16)v.y, (h16)v.z, (h16)v.w};
    *(h4v*)(p.dEmbC + i4) = o;
    return;
  }
  __shared__ h16 Ls[64][64];
  int mi, tile, Kd, Nd;
  if (bt < 768) { mi = bt >> 8; tile = bt & 255; Kd = 1024; Nd = 1024; }
  else { const int r = bt - 768; mi = 3 + (r >> 4); tile = r & 15; Kd = 256; Nd = 256; }
  const int ntn = Nd >> 6;
  const int tk = tile / ntn, tn = tile % ntn;
  const float* src = p.src[mi] + (long)(tk * 64) * Nd + tn * 64;
  h16* dst = p.dst[mi] + (long)(tn * 64) * Kd + tk * 64;
  #pragma unroll
  for (int it = 0; it < 4; ++it) {
    const int kr = (t >> 4) + it * 16;
    const int c4 = (t & 15) * 4;
    const float4 v = *(const float4*)(src + (long)kr * Nd + c4);
    const float vv[4] = {v.x, v.y, v.z, v.w};
    #pragma unroll
    for (int jj = 0; jj < 4; ++jj) {
      const int n = c4 + jj;
      Ls[n][(((kr >> 3) ^ ((n >> 3) & 7)) << 3) | (kr & 7)] = (h16)vv[jj];
    }
  }
  __syncthreads();
  #pragma unroll
  for (int it = 0; it < 2; ++it) {
    const int n = t >> 2;
    const int k8 = (t & 3) + it * 4;
    const h8v o = *(const h8v*)&Ls[n][(k8 ^ ((n >> 3) & 7)) << 3];
    *(h8v*)(dst + (long)n * Kd + k8 * 8) = o;
  }
}

// ---------------------------------------------------------------------------
// vtrans: Vbuf [b][2304][256] -> vT [b*8+h][32][2304] (per-head transposed),
// LDS-tiled 64kv x 32d, chunk-XOR swizzle, fully coalesced both sides.
// ---------------------------------------------------------------------------
__global__ __launch_bounds__(256) void vtrans(
    const h16* __restrict__ V, h16* __restrict__ vT)
{
  __shared__ h16 Ls[32][64];
  const int kc = blockIdx.x;           // 0..35
  const int bh = blockIdx.y;           // 0..31
  const int b = bh >> 3, h = bh & 7;
  const int t = threadIdx.x;
  const int kv0 = kc * 64;
  {
    const int row = t >> 2, c8 = t & 3;
    const h8v v = *(const h8v*)(V + ((long)b * Mm + kv0 + row) * Ee + h * 32 + c8 * 8);
    #pragma unroll
    for (int e = 0; e < 8; ++e) {
      const int d = c8 * 8 + e;
      Ls[d][(((row >> 3) ^ ((d >> 3) & 7)) << 3) | (row & 7)] = v[e];
    }
  }
  __syncthreads();
  {
    const int d = t >> 3, j8 = t & 7;
    const h8v o = *(const h8v*)&Ls[d][(j8 ^ ((d >> 3) & 7)) << 3];
    *(h8v*)(vT + ((long)bh * 32 + d) * Mm + kv0 + j8 * 8) = o;
  }
}

// ---------------------------------------------------------------------------
// fp16 MFMA GEMM. BN=128, BK=64, 256 threads. LDS pitch 64 halves with
// chunk-XOR swizzle col=(chunk^((row>>3)&7))*8 on both As and Bs (staging
// writes and fragment reads use the same map).
// BM=128: waves 2x2 (64x64 each, 4x4 frags). BM=64: waves 1x4 (64x32).
// TA=0: A h16 [m][k]; TA=1: A h16 [k][m] (scalar scatter, swizzle-spread).
// TB=1: B h16 [n][k] (vector); TB=0: B h16 [k][n] (scatter).
// AF32: A fp32 [m][k], converted in staging.
// Store: chunk=n>>OSHIFT selects O[z][chunk]; OUT16 dtype; RM = KV_S remap;
// STATS = per-z sum/sumsq atomics.
// ---------------------------------------------------------------------------
struct GemmP {
  const h16* A[4]; const h16* B[4]; void* O[4][3]; const float* A32[4];
};

template <int BM, int TA, int TB, int AF32, int OUT16, int RM, int STATS, int OSHIFT>
__global__ __launch_bounds__(256) void mg(GemmP p, int K, int lda, int ldb,
                                          int ldc, float* stats)
{
  __shared__ h16 As[BM][64];
  __shared__ h16 Bs[128][64];
  const int z = blockIdx.z;
  const h16* A = p.A[z]; const h16* B = p.B[z]; const float* A32 = p.A32[z];
  const int n0 = blockIdx.x * 128, m0 = blockIdx.y * BM;
  const int t = threadIdx.x, w = t >> 6, lg = (t >> 4) & 3, lr = t & 15;
  constexpr int MF = 4, NF = (BM == 128 ? 4 : 2);
  const int wm = (BM == 128) ? (w & 1) * 64 : 0;
  const int wn = (BM == 128) ? (w >> 1) * 64 : w * 32;

  f4v acc[MF][NF];
  #pragma unroll
  for (int i = 0; i < MF; ++i)
    #pragma unroll
    for (int j = 0; j < NF; ++j) acc[i][j] = (f4v){0.f, 0.f, 0.f, 0.f};

  for (int kt = 0; kt < K; kt += 64) {
    if (AF32) {
      #pragma unroll
      for (int it = 0; it < BM / 16; ++it) {
        const int f = t + it * 256, row = f >> 4, c4 = f & 15;
        const float4 v = *(const float4*)(A32 + (long)(m0 + row) * lda + kt + c4 * 4);
        h4v o = {(h16)v.x, (h16)v.y, (h16)v.z, (h16)v.w};
        const int col = ((((c4 >> 1) ^ ((row >> 3) & 7)) << 3) | ((c4 & 1) << 2));
        *(h4v*)&As[row][col] = o;
      }
    } else if (TA == 0) {
      #pragma unroll
      for (int it = 0; it < BM / 32; ++it) {
        const int f = t + it * 256, row = f >> 3, c8 = f & 7;
        *(h8v*)&As[row][(c8 ^ ((row >> 3) & 7)) << 3] =
            *(const h8v*)(A + (long)(m0 + row) * lda + kt + c8 * 8);
      }
    } else {
      #pragma unroll
      for (int it = 0; it < BM / 32; ++it) {
        const int f = t + it * 256;
        const int kr = (BM == 128) ? (f >> 4) : (f >> 3);
        const int mc = (BM == 128) ? (f & 15) : (f & 7);
        const h8v v = *(const h8v*)(A + (long)(kt + kr) * lda + m0 + mc * 8);
        const int colb = (((kr >> 3) ^ (mc & 7)) << 3) | (kr & 7);
        #pragma unroll
        for (int e = 0; e < 8; ++e) As[mc * 8 + e][colb] = v[e];
      }
    }
    if (TB == 0) {
      #pragma unroll
      for (int it = 0; it < 4; ++it) {
        const int f = t + it * 256, kr = f >> 4, nc = f & 15;
        const h8v v = *(const h8v*)(B + (long)(kt + kr) * ldb + n0 + nc * 8);
        const int colb = (((kr >> 3) ^ (nc & 7)) << 3) | (kr & 7);
        #pragma unroll
        for (int e = 0; e < 8; ++e) Bs[nc * 8 + e][colb] = v[e];
      }
    } else {
      #pragma unroll
      for (int it = 0; it < 4; ++it) {
        const int f = t + it * 256, row = f >> 3, c8 = f & 7;
        *(h8v*)&Bs[row][(c8 ^ ((row >> 3) & 7)) << 3] =
            *(const h8v*)(B + (long)(n0 + row) * ldb + kt + c8 * 8);
      }
    }
    __syncthreads();

    #pragma unroll
    for (int ks = 0; ks < 2; ++ks) {
      h8v af[MF], bf[NF];
      #pragma unroll
      for (int mf = 0; mf < MF; ++mf) {
        const int row = wm + mf * 16 + lr;
        af[mf] = *(const h8v*)&As[row][((ks * 4 + lg) ^ ((row >> 3) & 7)) << 3];
      }
      #pragma unroll
      for (int nf = 0; nf < NF; ++nf) {
        const int row = wn + nf * 16 + lr;
        bf[nf] = *(const h8v*)&Bs[row][((ks * 4 + lg) ^ ((row >> 3) & 7)) << 3];
      }
      #pragma unroll
      for (int mf = 0; mf < MF; ++mf)
        #pragma unroll
        for (int nf = 0; nf < NF; ++nf)
          acc[mf][nf] = __builtin_amdgcn_mfma_f32_16x16x32_f16(af[mf], bf[nf], acc[mf][nf], 0, 0, 0);
    }
    __syncthreads();
  }

  float s1 = 0.f, s2 = 0.f;
  #pragma unroll
  for (int mf = 0; mf < MF; ++mf)
    #pragma unroll
    for (int nf = 0; nf < NF; ++nf)
      #pragma unroll
      for (int r = 0; r < 4; ++r) {
        const int m = m0 + wm + mf * 16 + lg * 4 + r;
        const int n = n0 + wn + nf * 16 + lr;
        const float v = acc[mf][nf][r];
        if (STATS) { s1 += v; s2 += v * v; }
        if (RM) {
          ((h16*)p.O[z][0])[((long)(n >> 8) * Nn + m) * Ee + (n & 255)] = (h16)v;
        } else {
          const int chunk = n >> OSHIFT;
          const int col = n & ((1 << OSHIFT) - 1);
          if (OUT16) ((h16*)p.O[z][chunk])[(long)m * ldc + col] = (h16)v;
          else       ((float*)p.O[z][chunk])[(long)m * ldc + col] = v;
        }
      }
  if (STATS) {
    #pragma unroll
    for (int o = 1; o < 64; o <<= 1) { s1 += __shfl_xor(s1, o); s2 += __shfl_xor(s2, o); }
    if ((t & 63) == 0) { atomicAdd(&stats[z * 2], s1); atomicAdd(&stats[z * 2 + 1], s2); }
  }
}

// ---------------------------------------------------------------------------
// sim_c = softmax(attn_c * gamma1*rsqrt(var+eps), axis=-1) -> fp16.
// ---------------------------------------------------------------------------
__global__ __launch_bounds__(256) void softmax_c(
    const float* __restrict__ AC, const float* __restrict__ sums,
    const float* __restrict__ g1, h16* __restrict__ sim)
{
  __shared__ float red[256];
  const long r = blockIdx.x;
  const int b = (int)(r >> 10);
  const float* p = AC + r * Cc;
  const float invn = 1.f / (float)CCl;
  const float mean = sums[b * 2] * invn;
  const float var  = sums[b * 2 + 1] * invn - mean * mean;
  const float scb  = g1[0] * rsqrtf(var + EPSV);
  const int t = threadIdx.x;
  float4 v = ((const float4*)p)[t];
  v.x *= scb; v.y *= scb; v.z *= scb; v.w *= scb;
  float mx = fmaxf(fmaxf(v.x, v.y), fmaxf(v.z, v.w));
  red[t] = mx; __syncthreads();
  for (int s = 128; s > 0; s >>= 1) { if (t < s) red[t] = fmaxf(red[t], red[t + s]); __syncthreads(); }
  mx = red[0]; __syncthreads();
  v.x = __expf(v.x - mx); v.y = __expf(v.y - mx);
  v.z = __expf(v.z - mx); v.w = __expf(v.w - mx);
  red[t] = v.x + v.y + v.z + v.w; __syncthreads();
  for (int s = 128; s > 0; s >>= 1) { if (t < s) red[t] += red[t + s]; __syncthreads(); }
  const float inv = 1.f / red[0];
  h4v o = {(h16)(v.x * inv), (h16)(v.y * inv), (h16)(v.z * inv), (h16)(v.w * inv)};
  *(h4v*)&sim[r * Cc + t * 4] = o;
}

// ---------------------------------------------------------------------------
// 32x32 Gram + column sums (fp16 in, fp32 math) for analytic stage-2 scale.
// ---------------------------------------------------------------------------
__global__ __launch_bounds__(256) void gram_all(
    const h16* __restrict__ Kb, const h16* __restrict__ Qb,
    float* __restrict__ Gk, float* __restrict__ km,
    float* __restrict__ Gq, float* __restrict__ qm)
{
  const int blk = blockIdx.x;
  const h16* slab; int ntiles; float* gout; float* msum;
  if (blk < 32) {
    slab = Kb + ((long)(blk >> 3) * Mm) * Ee + (blk & 7) * 32;
    ntiles = 12; gout = Gk + (long)blk * 1024; msum = km + blk * 32;
  } else {
    const int i = blk - 32, qq = i >> 5, b = (i >> 3) & 3, hd = i & 7;
    slab = Qb + (long)qq * BNE + ((long)b * Nn) * Ee + hd * 32;
    ntiles = 3; gout = Gq + (long)i * 1024; msum = qm + i * 32;
  }
  __shared__ float Ks[192][36];
  const int t = threadIdx.x;
  const int d = t >> 3, e0 = (t & 7) * 4;
  float g0 = 0.f, g1 = 0.f, g2 = 0.f, g3 = 0.f, cm = 0.f;
  for (int tile = 0; tile < ntiles; ++tile) {
    __syncthreads();
    #pragma unroll
    for (int it = 0; it < 3; ++it) {
      const int f = t + it * 256, row = f >> 2, c8 = f & 3;
      const h8v v = *(const h8v*)(slab + (long)(tile * 192 + row) * Ee + c8 * 8);
      #pragma unroll
      for (int e = 0; e < 8; ++e) Ks[row][c8 * 8 + e] = (float)v[e];
    }
    __syncthreads();
    #pragma unroll 4
    for (int m = 0; m < 192; ++m) {
      const float qd = Ks[m][d];
      const float4 qe = *(const float4*)&Ks[m][e0];
      g0 = fmaf(qd, qe.x, g0); g1 = fmaf(qd, qe.y, g1);
      g2 = fmaf(qd, qe.z, g2); g3 = fmaf(qd, qe.w, g3);
    }
    if (t < 32) {
      #pragma unroll 4
      for (int m = 0; m < 192; ++m) cm += Ks[m][t];
    }
  }
  float* gp = gout + d * 32 + e0;
  gp[0] = g0; gp[1] = g1; gp[2] = g2; gp[3] = g3;
  if (t < 32) msum[t] = cm;
}

__global__ __launch_bounds__(256) void finalize_scale2(
    const float* __restrict__ Gq, const float* __restrict__ Gk,
    const float* __restrict__ qm, const float* __restrict__ km,
    const float* __restrict__ g2, float* __restrict__ sc2)
{
  __shared__ float red[4];
  const int i = blockIdx.x;            // 0..127 (q,b,h)
  const int kb = i & 31;
  const int t = threadIdx.x;
  const float4 a = *(const float4*)(Gq + (long)i * 1024 + t * 4);
  const float4 b = *(const float4*)(Gk + (long)kb * 1024 + t * 4);
  float s = a.x * b.x + a.y * b.y + a.z * b.z + a.w * b.w;
  #pragma unroll
  for (int o = 1; o < 64; o <<= 1) s += __shfl_xor(s, o);
  if ((t & 63) == 0) red[t >> 6] = s;
  float mu = 0.f;
  if (t < 32) mu = qm[i * 32 + t] * km[kb * 32 + t];
  #pragma unroll
  for (int o = 1; o < 32; o <<= 1) mu += __shfl_xor(mu, o);
  __syncthreads();
  if (t == 0) {
    const float tot = red[0] + red[1] + red[2] + red[3];
    const float inv = 1.f / ((float)Nn * (float)Mm);
    const float ex2 = tot * inv;
    const float m1  = mu * inv;
    sc2[i] = g2[i & 7] * rsqrtf(ex2 - m1 * m1 + EPSV) * LOG2E;  // exp2 domain
  }
}

// ---------------------------------------------------------------------------
// Barrier-free swapped-QK^T flash attention. Grid 1152 XCD-swizzled
// (x = pidx&7 = bh%8 -> all 36 blocks of one (b,h) share an XCD's L2).
// Q/K fragments direct from global; V from pre-transposed vT (contig 16B);
// P wave-local in LDS. NO __syncthreads anywhere. sc>0 assumed (gamma2=1).
// ---------------------------------------------------------------------------
__global__ __launch_bounds__(256) void flash4(
    const h16* __restrict__ Qb, const h16* __restrict__ Kb,
    const h16* __restrict__ vT, const float* __restrict__ sc2,
    h16* __restrict__ ctx)
{
  __shared__ h16 Ps[64][136];
  const int pidx = blockIdx.x;
  const int x = pidx & 7, rest = pidx >> 3;
  const int j = rest % 36, g = rest / 36;
  const int bh = g * 8 + x, b = bh >> 3, hd = bh & 7;
  const int nt = j % 9, q = j / 9;
  const int t = threadIdx.x, w = t >> 6, lg = (t >> 4) & 3, lr = t & 15;
  const float sc = sc2[(q << 5) + bh];

  const h16* Qp = Qb + (long)q * BNE + (long)(b * Nn + nt * 64) * Ee + hd * 32;
  const h16* Kp = Kb + ((long)b * Mm) * Ee + hd * 32;
  const h16* Vp = vT + (long)bh * (32L * Mm);

  const h8v qf = *(const h8v*)(Qp + (long)(w * 16 + lr) * Ee + lg * 8);

  float m_run = -3e38f, l_run = 0.f;
  f4v cacc[2];
  cacc[0] = (f4v){0.f, 0.f, 0.f, 0.f};
  cacc[1] = (f4v){0.f, 0.f, 0.f, 0.f};

  for (int mt = 0; mt < 18; ++mt) {
    f4v s[8];
    #pragma unroll
    for (int nf = 0; nf < 8; ++nf) {
      const h8v kf = *(const h8v*)(Kp + (long)(mt * 128 + nf * 16 + lr) * Ee + lg * 8);
      s[nf] = __builtin_amdgcn_mfma_f32_16x16x32_f16(kf, qf, (f4v){0.f, 0.f, 0.f, 0.f}, 0, 0, 0);
    }
    // in-lane online softmax for q-row lr (raw-domain max; sc > 0)
    float mx = -3e38f;
    #pragma unroll
    for (int nf = 0; nf < 8; ++nf)
      #pragma unroll
      for (int r = 0; r < 4; ++r) mx = fmaxf(mx, s[nf][r]);
    mx = fmaxf(mx, __shfl_xor(mx, 16));
    mx = fmaxf(mx, __shfl_xor(mx, 32));
    const float mnew = fmaxf(m_run, mx * sc);
    const float corr = __builtin_amdgcn_exp2f(m_run - mnew);
    float rs = 0.f;
    #pragma unroll
    for (int nf = 0; nf < 8; ++nf)
      #pragma unroll
      for (int r = 0; r < 4; ++r) {
        const float pv = __builtin_amdgcn_exp2f(fmaf(s[nf][r], sc, -mnew));
        s[nf][r] = pv; rs += pv;
      }
    rs += __shfl_xor(rs, 16);
    rs += __shfl_xor(rs, 32);
    l_run = l_run * corr + rs;
    m_run = mnew;
    #pragma unroll
    for (int r = 0; r < 4; ++r) {
      const float cr = __shfl(corr, lg * 4 + r);
      cacc[0][r] *= cr; cacc[1][r] *= cr;
    }
    // P -> LDS (wave-local rows; no barrier)
    #pragma unroll
    for (int nf = 0; nf < 8; ++nf) {
      h4v pk = {(h16)s[nf][0], (h16)s[nf][1], (h16)s[nf][2], (h16)s[nf][3]};
      *(h4v*)&Ps[w * 16 + lr][nf * 16 + lg * 4] = pk;
    }
    // ctx += P V  (V fragments direct from transposed global, 16B contig)
    #pragma unroll
    for (int ks = 0; ks < 4; ++ks) {
      const h8v pf = *(const h8v*)&Ps[w * 16 + lr][ks * 32 + lg * 8];
      #pragma unroll
      for (int df = 0; df < 2; ++df) {
        const h8v vf = *(const h8v*)(Vp + (long)(df * 16 + lr) * Mm + mt * 128 + ks * 32 + lg * 8);
        cacc[df] = __builtin_amdgcn_mfma_f32_16x16x32_f16(pf, vf, cacc[df], 0, 0, 0);
      }
    }
  }

  float linv[4];
  #pragma unroll
  for (int r = 0; r < 4; ++r) linv[r] = 1.f / __shfl(l_run, lg * 4 + r);
  h16* Op = ctx + (long)q * BNE + (long)(b * Nn + nt * 64) * Ee + hd * 32;
  #pragma unroll
  for (int r = 0; r < 4; ++r) {
    const long row = w * 16 + lg * 4 + r;
    Op[row * Ee + 0  + lr] = (h16)(cacc[0][r] * linv[r]);
    Op[row * Ee + 16 + lr] = (h16)(cacc[1][r] * linv[r]);
  }
}

// ---------------------------------------------------------------------------
// Launcher. Workspace (halves), same ~44 MB footprint:
//  [0]        embC16 -> KVS16 -> vT (all 2359296)
//  [2359296]  QC16 -> sim16 ; [4718592] KC16 (sim spills into it, 4194304 tot)
//  [7077888]  VC16 -> ctx16
//  [9437184]  attn_c fp32 (8388608 h) -> Kbuf/Vbuf/Qbuf fp16
//  [17825792] WcT 3145728 | WkvT 131072 | WqT 262144 | WoT 262144
//  [21626880] stats fp32 (sums 8, Gk 32768, km 1024, Gq 131072, qm 4096, sc2 128)
// ---------------------------------------------------------------------------
extern "C" void kernel_launch(void* const* d_in, const int* in_sizes, int n_in,
                              void* d_out, int out_size, void* d_ws, size_t ws_size,
                              hipStream_t stream)
{
  (void)in_sizes; (void)n_in; (void)out_size; (void)ws_size;
  const float* emb[4] = {(const float*)d_in[0], (const float*)d_in[1],
                         (const float*)d_in[2], (const float*)d_in[3]};
  const float* gamma1 = (const float*)d_in[18];
  const float* gamma2 = (const float*)d_in[20];
  float* out = (float*)d_out;

  h16* hws = (h16*)d_ws;
  h16* embC16 = hws;
  h16* QC16   = hws + 2359296L;
  h16* KC16   = hws + 4718592L;
  h16* VC16   = hws + 7077888L;
  h16* attnR  = hws + 9437184L;
  float* attnC = (float*)attnR;
  h16* WcT  = hws + 17825792L;
  h16* WkvT = WcT + 3145728L;
  h16* WqT  = WkvT + 131072L;
  h16* WoT  = WqT + 262144L;
  float* stats = (float*)(hws + 21626880L);
  float* sums = stats;
  float* Gk   = stats + 8;
  float* km   = Gk + 32768;
  float* Gq   = km + 1024;
  float* qm   = Gq + 131072;
  float* sc2v = qm + 4096;
  // aliases (lifetimes verified against launch order)
  h16* sim16  = QC16;
  h16* KVS16  = embC16;
  h16* Kbuf16 = attnR;
  h16* Vbuf16 = attnR + 2359296L;
  h16* Qbuf16 = attnR + 4718592L;
  h16* vT     = embC16;     // after KV-proj consumes KVS16
  h16* ctx16  = VC16;

  hipMemsetAsync(sums, 0, 8 * sizeof(float), stream);

  {
    WtP wp;
    wp.src[0] = (const float*)d_in[5];  wp.dst[0] = WcT;                 // WqC
    wp.src[1] = (const float*)d_in[6];  wp.dst[1] = WcT + 1048576L;      // WkC
    wp.src[2] = (const float*)d_in[7];  wp.dst[2] = WcT + 2097152L;      // WvC
    wp.src[3] = (const float*)d_in[12]; wp.dst[3] = WkvT;                // Wk
    wp.src[4] = (const float*)d_in[13]; wp.dst[4] = WkvT + 65536L;       // Wv
    for (int i = 0; i < 4; ++i) {
      wp.src[5 + i] = (const float*)d_in[8 + i];  wp.dst[5 + i] = WqT + (long)i * 65536;
      wp.src[9 + i] = (const float*)d_in[14 + i]; wp.dst[9 + i] = WoT + (long)i * 65536;
    }
    wp.embC = (const float*)d_in[4]; wp.dEmbC = embC16;
    wtrans<<<3232, 256, 0, stream>>>(wp);
  }

  // Stage A: [QC|KC|VC]16 = embC16 @ Wc   (2304 x 3072 x 1024), B transposed
  {
    GemmP gp{};
    gp.A[0] = embC16; gp.B[0] = WcT;
    gp.O[0][0] = QC16; gp.O[0][1] = KC16; gp.O[0][2] = VC16;
    mg<128,0,1,0,1,0,0,10><<<dim3(24,18,1), 256, 0, stream>>>(gp, 1024, 1024, 1024, 1024, nullptr);
  }
  // attn_c[b] = QC^T @ KC (1024x1024x576) fp32 + fused stats
  {
    GemmP gp{};
    for (int z = 0; z < 4; ++z) {
      gp.A[z] = QC16 + (long)z * 589824; gp.B[z] = KC16 + (long)z * 589824;
      gp.O[z][0] = attnC + (long)z * CCl;
    }
    mg<128,1,0,0,0,0,1,30><<<dim3(8,8,4), 256, 0, stream>>>(gp, 576, 1024, 1024, 1024, sums);
  }
  softmax_c<<<4096, 256, 0, stream>>>(attnC, sums, gamma1, sim16);
  // T_hat[b] = VC @ sim^T -> KV_S layout fp16 (576x1024x1024)
  {
    GemmP gp{};
    for (int z = 0; z < 4; ++z) {
      gp.A[z] = VC16 + (long)z * 589824; gp.B[z] = sim16 + (long)z * CCl;
      gp.O[z][0] = KVS16 + (long)z * 589824;
    }
    mg<64,0,1,0,1,1,0,30><<<dim3(8,9,4), 256, 0, stream>>>(gp, 1024, 1024, 1024, 256, nullptr);
  }
  // K/V projections: (9216 x 512 x 256), B transposed
  {
    GemmP gp{};
    gp.A[0] = KVS16; gp.B[0] = WkvT;
    gp.O[0][0] = Kbuf16; gp.O[0][1] = Vbuf16;
    mg<128,0,1,0,1,0,0,8><<<dim3(4,72,1), 256, 0, stream>>>(gp, 256, 256, 256, 256, nullptr);
  }
  // Q projections: 4 x (2304 x 256 x 256), A fp32, B transposed
  {
    GemmP gp{};
    for (int z = 0; z < 4; ++z) {
      gp.A32[z] = emb[z]; gp.B[z] = WqT + (long)z * 65536;
      gp.O[z][0] = Qbuf16 + (long)z * 589824;
    }
    mg<64,0,1,1,1,0,0,30><<<dim3(2,36,4), 256, 0, stream>>>(gp, 256, 256, 256, 256, nullptr);
  }
  // V pre-transpose for flash (KVS16 dead -> vT aliases it)
  vtrans<<<dim3(36,32), 256, 0, stream>>>(Vbuf16, vT);
  // analytic inorm scales for stage-2 attention
  gram_all<<<160, 256, 0, stream>>>(Kbuf16, Qbuf16, Gk, km, Gq, qm);
  finalize_scale2<<<128, 256, 0, stream>>>(Gq, Gk, qm, km, gamma2, sc2v);
  // flash attention -> ctx (4,B,N,E)
  flash4<<<1152, 256, 0, stream>>>(Qbuf16, Kbuf16, vT, sc2v, ctx16);
  // output projections: 4 x (2304 x 256 x 256) -> fp32 d_out, B transposed
  {
    GemmP gp{};
    for (int z = 0; z < 4; ++z) {
      gp.A[z] = ctx16 + (long)z * 589824; gp.B[z] = WoT + (long)z * 65536;
      gp.O[z][0] = out + (long)z * 589824;
    }
    mg<64,0,1,0,0,0,0,30><<<dim3(2,36,4), 256, 0, stream>>>(gp, 256, 256, 256, 256, nullptr);
  }
}

// Round 6
// 427.287 us; speedup vs baseline: 1.1832x; 1.1832x over previous
//
#include <hip/hip_runtime.h>
#include <math.h>

// ---------------------------------------------------------------------------
// UDTransNet fused forward. fp16 MFMA everywhere (fp32 accum), fp16
// intermediates, transposed weights, reg-prefetch double-buffered staging.
// Sizes: B=4, N=576, E=256, C=4E=1024, H=8, dh=32, M=4N=2304.
// ---------------------------------------------------------------------------

namespace {
constexpr int Bq  = 4;
constexpr int Nn  = 576;
constexpr int Ee  = 256;
constexpr int Cc  = 1024;
constexpr int Mm  = 2304;
constexpr long BNE = (long)Bq * Nn * Ee;     // 589824
constexpr long CCl = (long)Cc * Cc;          // 1048576
constexpr float EPSV = 1e-3f;
constexpr float LOG2E = 1.4426950408889634f;
} // namespace

typedef _Float16 h16;
typedef _Float16 h8v __attribute__((ext_vector_type(8)));
typedef _Float16 h4v __attribute__((ext_vector_type(4)));
typedef float    f4v __attribute__((ext_vector_type(4)));

// ---------------------------------------------------------------------------
// wtrans: weights fp32[K][N] -> h16[N][K] (64x64 LDS tiles, chunk-XOR
// swizzle) + straight fp32->fp16 copy of emb_C.
// ---------------------------------------------------------------------------
struct WtP {
  const float* src[13]; h16* dst[13];
  const float* embC; h16* dEmbC;
};

__global__ __launch_bounds__(256) void wtrans(WtP p)
{
  const int bt = blockIdx.x;
  const int t = threadIdx.x;
  if (bt >= 928) {
    const long i4 = ((long)(bt - 928) * 256 + t) * 4;
    const float4 v = *(const float4*)(p.embC + i4);
    h4v o = {(h16)v.x, (h16)v.y, (h16)v.z, (h16)v.w};
    *(h4v*)(p.dEmbC + i4) = o;
    return;
  }
  __shared__ h16 Ls[64][64];
  int mi, tile, Kd, Nd;
  if (bt < 768) { mi = bt >> 8; tile = bt & 255; Kd = 1024; Nd = 1024; }
  else { const int r = bt - 768; mi = 3 + (r >> 4); tile = r & 15; Kd = 256; Nd = 256; }
  const int ntn = Nd >> 6;
  const int tk = tile / ntn, tn = tile % ntn;
  const float* src = p.src[mi] + (long)(tk * 64) * Nd + tn * 64;
  h16* dst = p.dst[mi] + (long)(tn * 64) * Kd + tk * 64;
  #pragma unroll
  for (int it = 0; it < 4; ++it) {
    const int kr = (t >> 4) + it * 16;
    const int c4 = (t & 15) * 4;
    const float4 v = *(const float4*)(src + (long)kr * Nd + c4);
    const float vv[4] = {v.x, v.y, v.z, v.w};
    #pragma unroll
    for (int jj = 0; jj < 4; ++jj) {
      const int n = c4 + jj;
      Ls[n][(((kr >> 3) ^ ((n >> 3) & 7)) << 3) | (kr & 7)] = (h16)vv[jj];
    }
  }
  __syncthreads();
  #pragma unroll
  for (int it = 0; it < 2; ++it) {
    const int n = t >> 2;
    const int k8 = (t & 3) + it * 4;
    const h8v o = *(const h8v*)&Ls[n][(k8 ^ ((n >> 3) & 7)) << 3];
    *(h8v*)(dst + (long)n * Kd + k8 * 8) = o;
  }
}

// ---------------------------------------------------------------------------
// vtrans: Vbuf [b][2304][256] -> vT [b*8+h][32][2304].
// ---------------------------------------------------------------------------
__global__ __launch_bounds__(256) void vtrans(
    const h16* __restrict__ V, h16* __restrict__ vT)
{
  __shared__ h16 Ls[32][64];
  const int kc = blockIdx.x;           // 0..35
  const int bh = blockIdx.y;           // 0..31
  const int b = bh >> 3, h = bh & 7;
  const int t = threadIdx.x;
  const int kv0 = kc * 64;
  {
    const int row = t >> 2, c8 = t & 3;
    const h8v v = *(const h8v*)(V + ((long)b * Mm + kv0 + row) * Ee + h * 32 + c8 * 8);
    #pragma unroll
    for (int e = 0; e < 8; ++e) {
      const int d = c8 * 8 + e;
      Ls[d][(((row >> 3) ^ ((d >> 3) & 7)) << 3) | (row & 7)] = v[e];
    }
  }
  __syncthreads();
  {
    const int d = t >> 3, j8 = t & 7;
    const h8v o = *(const h8v*)&Ls[d][(j8 ^ ((d >> 3) & 7)) << 3];
    *(h8v*)(vT + ((long)bh * 32 + d) * Mm + kv0 + j8 * 8) = o;
  }
}

// ---------------------------------------------------------------------------
// fp16 MFMA GEMM with register-prefetch double buffering (T14 async split):
// issue next K-tile's global loads into regs BEFORE the MFMA phase; write
// them to LDS after the post-compute barrier. BN=128, BK=64, 256 threads.
// LDS pitch 64 halves, chunk-XOR swizzle on writes and fragment reads.
// BM=128: waves 2x2 (64x64). BM=64: waves 1x4 (64x32).
// TA=0: A h16 [m][k]; TA=1: A h16 [k][m]. TB=1: B h16 [n][k]; TB=0: [k][n].
// AF32: A fp32 [m][k]. Store: chunk=n>>OSHIFT picks O[z][chunk]; OUT16;
// RM = KV_S remap; STATS = per-z sum/sumsq atomics.
// ---------------------------------------------------------------------------
struct GemmP {
  const h16* A[4]; const h16* B[4]; void* O[4][3]; const float* A32[4];
};

template <int BM, int TA, int TB, int AF32, int OUT16, int RM, int STATS, int OSHIFT>
__global__ __launch_bounds__(256) void mg(GemmP p, int K, int lda, int ldb,
                                          int ldc, float* stats)
{
  __shared__ h16 As[BM][64];
  __shared__ h16 Bs[128][64];
  const int z = blockIdx.z;
  const h16* A = p.A[z]; const h16* B = p.B[z]; const float* A32 = p.A32[z];
  const int n0 = blockIdx.x * 128, m0 = blockIdx.y * BM;
  const int t = threadIdx.x, w = t >> 6, lg = (t >> 4) & 3, lr = t & 15;
  constexpr int MF = 4, NF = (BM == 128 ? 4 : 2);
  const int wm = (BM == 128) ? (w & 1) * 64 : 0;
  const int wn = (BM == 128) ? (w >> 1) * 64 : w * 32;

  h8v   rA[AF32 ? 1 : BM / 32];
  float4 rF[AF32 ? BM / 16 : 1];
  h8v   rB[4];

  auto LOAD = [&](int kt) {
    if constexpr (AF32) {
      #pragma unroll
      for (int it = 0; it < BM / 16; ++it) {
        const int f = t + it * 256, row = f >> 4, c4 = f & 15;
        rF[it] = *(const float4*)(A32 + (long)(m0 + row) * lda + kt + c4 * 4);
      }
    } else if constexpr (TA == 0) {
      #pragma unroll
      for (int it = 0; it < BM / 32; ++it) {
        const int f = t + it * 256, row = f >> 3, c8 = f & 7;
        rA[it] = *(const h8v*)(A + (long)(m0 + row) * lda + kt + c8 * 8);
      }
    } else {
      #pragma unroll
      for (int it = 0; it < BM / 32; ++it) {
        const int f = t + it * 256;
        const int kr = (BM == 128) ? (f >> 4) : (f >> 3);
        const int mc = (BM == 128) ? (f & 15) : (f & 7);
        rA[it] = *(const h8v*)(A + (long)(kt + kr) * lda + m0 + mc * 8);
      }
    }
    if constexpr (TB == 0) {
      #pragma unroll
      for (int it = 0; it < 4; ++it) {
        const int f = t + it * 256, kr = f >> 4, nc = f & 15;
        rB[it] = *(const h8v*)(B + (long)(kt + kr) * ldb + n0 + nc * 8);
      }
    } else {
      #pragma unroll
      for (int it = 0; it < 4; ++it) {
        const int f = t + it * 256, row = f >> 3, c8 = f & 7;
        rB[it] = *(const h8v*)(B + (long)(n0 + row) * ldb + kt + c8 * 8);
      }
    }
  };

  auto STORE = [&]() {
    if constexpr (AF32) {
      #pragma unroll
      for (int it = 0; it < BM / 16; ++it) {
        const int f = t + it * 256, row = f >> 4, c4 = f & 15;
        const float4 v = rF[it];
        h4v o = {(h16)v.x, (h16)v.y, (h16)v.z, (h16)v.w};
        const int col = ((((c4 >> 1) ^ ((row >> 3) & 7)) << 3) | ((c4 & 1) << 2));
        *(h4v*)&As[row][col] = o;
      }
    } else if constexpr (TA == 0) {
      #pragma unroll
      for (int it = 0; it < BM / 32; ++it) {
        const int f = t + it * 256, row = f >> 3, c8 = f & 7;
        *(h8v*)&As[row][(c8 ^ ((row >> 3) & 7)) << 3] = rA[it];
      }
    } else {
      #pragma unroll
      for (int it = 0; it < BM / 32; ++it) {
        const int f = t + it * 256;
        const int kr = (BM == 128) ? (f >> 4) : (f >> 3);
        const int mc = (BM == 128) ? (f & 15) : (f & 7);
        const int colb = (((kr >> 3) ^ (mc & 7)) << 3) | (kr & 7);
        #pragma unroll
        for (int e = 0; e < 8; ++e) As[mc * 8 + e][colb] = rA[it][e];
      }
    }
    if constexpr (TB == 0) {
      #pragma unroll
      for (int it = 0; it < 4; ++it) {
        const int f = t + it * 256, kr = f >> 4, nc = f & 15;
        const int colb = (((kr >> 3) ^ (nc & 7)) << 3) | (kr & 7);
        #pragma unroll
        for (int e = 0; e < 8; ++e) Bs[nc * 8 + e][colb] = rB[it][e];
      }
    } else {
      #pragma unroll
      for (int it = 0; it < 4; ++it) {
        const int f = t + it * 256, row = f >> 3, c8 = f & 7;
        *(h8v*)&Bs[row][(c8 ^ ((row >> 3) & 7)) << 3] = rB[it];
      }
    }
  };

  f4v acc[MF][NF];
  #pragma unroll
  for (int i = 0; i < MF; ++i)
    #pragma unroll
    for (int j = 0; j < NF; ++j) acc[i][j] = (f4v){0.f, 0.f, 0.f, 0.f};

  LOAD(0);
  STORE();
  __syncthreads();

  for (int kt = 0;;) {
    const int ktn = kt + 64;
    const bool more = ktn < K;
    if (more) LOAD(ktn);                       // overlap with MFMA below

    #pragma unroll
    for (int ks = 0; ks < 2; ++ks) {
      h8v af[MF], bf[NF];
      #pragma unroll
      for (int mf = 0; mf < MF; ++mf) {
        const int row = wm + mf * 16 + lr;
        af[mf] = *(const h8v*)&As[row][((ks * 4 + lg) ^ ((row >> 3) & 7)) << 3];
      }
      #pragma unroll
      for (int nf = 0; nf < NF; ++nf) {
        const int row = wn + nf * 16 + lr;
        bf[nf] = *(const h8v*)&Bs[row][((ks * 4 + lg) ^ ((row >> 3) & 7)) << 3];
      }
      #pragma unroll
      for (int mf = 0; mf < MF; ++mf)
        #pragma unroll
        for (int nf = 0; nf < NF; ++nf)
          acc[mf][nf] = __builtin_amdgcn_mfma_f32_16x16x32_f16(af[mf], bf[nf], acc[mf][nf], 0, 0, 0);
    }
    if (!more) break;
    __syncthreads();                           // all LDS reads done
    STORE();
    __syncthreads();                           // LDS ready
    kt = ktn;
  }

  float s1 = 0.f, s2 = 0.f;
  #pragma unroll
  for (int mf = 0; mf < MF; ++mf)
    #pragma unroll
    for (int nf = 0; nf < NF; ++nf)
      #pragma unroll
      for (int r = 0; r < 4; ++r) {
        const int m = m0 + wm + mf * 16 + lg * 4 + r;
        const int n = n0 + wn + nf * 16 + lr;
        const float v = acc[mf][nf][r];
        if (STATS) { s1 += v; s2 += v * v; }
        if (RM) {
          ((h16*)p.O[z][0])[((long)(n >> 8) * Nn + m) * Ee + (n & 255)] = (h16)v;
        } else {
          const int chunk = n >> OSHIFT;
          const int col = n & ((1 << OSHIFT) - 1);
          if (OUT16) ((h16*)p.O[z][chunk])[(long)m * ldc + col] = (h16)v;
          else       ((float*)p.O[z][chunk])[(long)m * ldc + col] = v;
        }
      }
  if (STATS) {
    #pragma unroll
    for (int o = 1; o < 64; o <<= 1) { s1 += __shfl_xor(s1, o); s2 += __shfl_xor(s2, o); }
    if ((t & 63) == 0) { atomicAdd(&stats[z * 2], s1); atomicAdd(&stats[z * 2 + 1], s2); }
  }
}

// ---------------------------------------------------------------------------
// sim_c = softmax(attn_c * gamma1*rsqrt(var+eps), axis=-1) -> fp16.
// ---------------------------------------------------------------------------
__global__ __launch_bounds__(256) void softmax_c(
    const float* __restrict__ AC, const float* __restrict__ sums,
    const float* __restrict__ g1, h16* __restrict__ sim)
{
  __shared__ float red[256];
  const long r = blockIdx.x;
  const int b = (int)(r >> 10);
  const float* p = AC + r * Cc;
  const float invn = 1.f / (float)CCl;
  const float mean = sums[b * 2] * invn;
  const float var  = sums[b * 2 + 1] * invn - mean * mean;
  const float scb  = g1[0] * rsqrtf(var + EPSV);
  const int t = threadIdx.x;
  float4 v = ((const float4*)p)[t];
  v.x *= scb; v.y *= scb; v.z *= scb; v.w *= scb;
  float mx = fmaxf(fmaxf(v.x, v.y), fmaxf(v.z, v.w));
  red[t] = mx; __syncthreads();
  for (int s = 128; s > 0; s >>= 1) { if (t < s) red[t] = fmaxf(red[t], red[t + s]); __syncthreads(); }
  mx = red[0]; __syncthreads();
  v.x = __expf(v.x - mx); v.y = __expf(v.y - mx);
  v.z = __expf(v.z - mx); v.w = __expf(v.w - mx);
  red[t] = v.x + v.y + v.z + v.w; __syncthreads();
  for (int s = 128; s > 0; s >>= 1) { if (t < s) red[t] += red[t + s]; __syncthreads(); }
  const float inv = 1.f / red[0];
  h4v o = {(h16)(v.x * inv), (h16)(v.y * inv), (h16)(v.z * inv), (h16)(v.w * inv)};
  *(h4v*)&sim[r * Cc + t * 4] = o;
}

// ---------------------------------------------------------------------------
// 32x32 Gram + column sums (fp16 in, fp32 math) for analytic stage-2 scale.
// ---------------------------------------------------------------------------
__global__ __launch_bounds__(256) void gram_all(
    const h16* __restrict__ Kb, const h16* __restrict__ Qb,
    float* __restrict__ Gk, float* __restrict__ km,
    float* __restrict__ Gq, float* __restrict__ qm)
{
  const int blk = blockIdx.x;
  const h16* slab; int ntiles; float* gout; float* msum;
  if (blk < 32) {
    slab = Kb + ((long)(blk >> 3) * Mm) * Ee + (blk & 7) * 32;
    ntiles = 12; gout = Gk + (long)blk * 1024; msum = km + blk * 32;
  } else {
    const int i = blk - 32, qq = i >> 5, b = (i >> 3) & 3, hd = i & 7;
    slab = Qb + (long)qq * BNE + ((long)b * Nn) * Ee + hd * 32;
    ntiles = 3; gout = Gq + (long)i * 1024; msum = qm + i * 32;
  }
  __shared__ float Ks[192][36];
  const int t = threadIdx.x;
  const int d = t >> 3, e0 = (t & 7) * 4;
  float g0 = 0.f, g1 = 0.f, g2 = 0.f, g3 = 0.f, cm = 0.f;
  for (int tile = 0; tile < ntiles; ++tile) {
    __syncthreads();
    #pragma unroll
    for (int it = 0; it < 3; ++it) {
      const int f = t + it * 256, row = f >> 2, c8 = f & 3;
      const h8v v = *(const h8v*)(slab + (long)(tile * 192 + row) * Ee + c8 * 8);
      #pragma unroll
      for (int e = 0; e < 8; ++e) Ks[row][c8 * 8 + e] = (float)v[e];
    }
    __syncthreads();
    #pragma unroll 4
    for (int m = 0; m < 192; ++m) {
      const float qd = Ks[m][d];
      const float4 qe = *(const float4*)&Ks[m][e0];
      g0 = fmaf(qd, qe.x, g0); g1 = fmaf(qd, qe.y, g1);
      g2 = fmaf(qd, qe.z, g2); g3 = fmaf(qd, qe.w, g3);
    }
    if (t < 32) {
      #pragma unroll 4
      for (int m = 0; m < 192; ++m) cm += Ks[m][t];
    }
  }
  float* gp = gout + d * 32 + e0;
  gp[0] = g0; gp[1] = g1; gp[2] = g2; gp[3] = g3;
  if (t < 32) msum[t] = cm;
}

__global__ __launch_bounds__(256) void finalize_scale2(
    const float* __restrict__ Gq, const float* __restrict__ Gk,
    const float* __restrict__ qm, const float* __restrict__ km,
    const float* __restrict__ g2, float* __restrict__ sc2)
{
  __shared__ float red[4];
  const int i = blockIdx.x;            // 0..127 (q,b,h)
  const int kb = i & 31;
  const int t = threadIdx.x;
  const float4 a = *(const float4*)(Gq + (long)i * 1024 + t * 4);
  const float4 b = *(const float4*)(Gk + (long)kb * 1024 + t * 4);
  float s = a.x * b.x + a.y * b.y + a.z * b.z + a.w * b.w;
  #pragma unroll
  for (int o = 1; o < 64; o <<= 1) s += __shfl_xor(s, o);
  if ((t & 63) == 0) red[t >> 6] = s;
  float mu = 0.f;
  if (t < 32) mu = qm[i * 32 + t] * km[kb * 32 + t];
  #pragma unroll
  for (int o = 1; o < 32; o <<= 1) mu += __shfl_xor(mu, o);
  __syncthreads();
  if (t == 0) {
    const float tot = red[0] + red[1] + red[2] + red[3];
    const float inv = 1.f / ((float)Nn * (float)Mm);
    const float ex2 = tot * inv;
    const float m1  = mu * inv;
    sc2[i] = g2[i & 7] * rsqrtf(ex2 - m1 * m1 + EPSV) * LOG2E;  // exp2 domain
  }
}

// ---------------------------------------------------------------------------
// flash5: swapped-QK^T MFMA flash attention, K+Vt staged in LDS (loaded once
// per block, shared by 4 waves), register-prefetch double buffering (stage
// issue before compute, LDS write between barriers after compute).
// Odd LDS pitches (K:40, Vt/Ps:136 halves) -> all b128 accesses conflict-free.
// Grid 1152 XCD-swizzled. P wave-local (no barrier for P). sc>0 assumed.
// ---------------------------------------------------------------------------
__global__ __launch_bounds__(256) void flash5(
    const h16* __restrict__ Qb, const h16* __restrict__ Kb,
    const h16* __restrict__ vT, const float* __restrict__ sc2,
    h16* __restrict__ ctx)
{
  __shared__ h16 Ks[128][40];
  __shared__ h16 Vt[32][136];
  __shared__ h16 Ps[64][136];
  const int pidx = blockIdx.x;
  const int x = pidx & 7, rest = pidx >> 3;
  const int j = rest % 36, g = rest / 36;
  const int bh = g * 8 + x, b = bh >> 3, hd = bh & 7;
  const int nt = j % 9, q = j / 9;
  const int t = threadIdx.x, w = t >> 6, lg = (t >> 4) & 3, lr = t & 15;
  const float sc = sc2[(q << 5) + bh];

  const h16* Qp = Qb + (long)q * BNE + (long)(b * Nn + nt * 64) * Ee + hd * 32;
  const h16* Kp = Kb + ((long)b * Mm) * Ee + hd * 32;
  const h16* Vp = vT + (long)bh * (32L * Mm);

  const h8v qf = *(const h8v*)(Qp + (long)(w * 16 + lr) * Ee + lg * 8);

  const int krow = t >> 1, kc = (t & 1) * 16;   // K staging: 2 h8v / thread
  const int vd   = t >> 3, vc = (t & 7) * 16;   // Vt staging: 2 h8v / thread

  h8v ka0, ka1, va0, va1;
  ka0 = *(const h8v*)(Kp + (long)krow * Ee + kc);
  ka1 = *(const h8v*)(Kp + (long)krow * Ee + kc + 8);
  va0 = *(const h8v*)(Vp + (long)vd * Mm + vc);
  va1 = *(const h8v*)(Vp + (long)vd * Mm + vc + 8);
  *(h8v*)&Ks[krow][kc]     = ka0;
  *(h8v*)&Ks[krow][kc + 8] = ka1;
  *(h8v*)&Vt[vd][vc]       = va0;
  *(h8v*)&Vt[vd][vc + 8]   = va1;

  float m_run = -3e38f, l_run = 0.f;
  f4v cacc[2];
  cacc[0] = (f4v){0.f, 0.f, 0.f, 0.f};
  cacc[1] = (f4v){0.f, 0.f, 0.f, 0.f};
  __syncthreads();

  for (int mt = 0; mt < 18; ++mt) {
    const bool more = mt < 17;
    if (more) {                                 // issue next-tile loads early
      const long ko = (long)((mt + 1) * 128 + krow) * Ee + kc;
      ka0 = *(const h8v*)(Kp + ko);
      ka1 = *(const h8v*)(Kp + ko + 8);
      const long vo = (long)vd * Mm + (mt + 1) * 128 + vc;
      va0 = *(const h8v*)(Vp + vo);
      va1 = *(const h8v*)(Vp + vo + 8);
    }

    // S = K Q^T from LDS (lane owns q-row lr, 32 kv logits)
    f4v s[8];
    #pragma unroll
    for (int nf = 0; nf < 8; ++nf) {
      const h8v kf = *(const h8v*)&Ks[nf * 16 + lr][lg * 8];
      s[nf] = __builtin_amdgcn_mfma_f32_16x16x32_f16(kf, qf, (f4v){0.f, 0.f, 0.f, 0.f}, 0, 0, 0);
    }
    // in-lane online softmax (raw-domain max; sc > 0)
    float mx = -3e38f;
    #pragma unroll
    for (int nf = 0; nf < 8; ++nf)
      #pragma unroll
      for (int r = 0; r < 4; ++r) mx = fmaxf(mx, s[nf][r]);
    mx = fmaxf(mx, __shfl_xor(mx, 16));
    mx = fmaxf(mx, __shfl_xor(mx, 32));
    const float mnew = fmaxf(m_run, mx * sc);
    const float corr = __builtin_amdgcn_exp2f(m_run - mnew);
    float rs = 0.f;
    #pragma unroll
    for (int nf = 0; nf < 8; ++nf)
      #pragma unroll
      for (int r = 0; r < 4; ++r) {
        const float pv = __builtin_amdgcn_exp2f(fmaf(s[nf][r], sc, -mnew));
        s[nf][r] = pv; rs += pv;
      }
    rs += __shfl_xor(rs, 16);
    rs += __shfl_xor(rs, 32);
    l_run = l_run * corr + rs;
    m_run = mnew;
    #pragma unroll
    for (int r = 0; r < 4; ++r) {
      const float cr = __shfl(corr, lg * 4 + r);
      cacc[0][r] *= cr; cacc[1][r] *= cr;
    }
    // P -> LDS (wave-local rows; no barrier)
    #pragma unroll
    for (int nf = 0; nf < 8; ++nf) {
      h4v pk = {(h16)s[nf][0], (h16)s[nf][1], (h16)s[nf][2], (h16)s[nf][3]};
      *(h4v*)&Ps[w * 16 + lr][nf * 16 + lg * 4] = pk;
    }
    // ctx += P V from LDS
    #pragma unroll
    for (int ks = 0; ks < 4; ++ks) {
      const h8v pf = *(const h8v*)&Ps[w * 16 + lr][ks * 32 + lg * 8];
      #pragma unroll
      for (int df = 0; df < 2; ++df) {
        const h8v vf = *(const h8v*)&Vt[df * 16 + lr][ks * 32 + lg * 8];
        cacc[df] = __builtin_amdgcn_mfma_f32_16x16x32_f16(pf, vf, cacc[df], 0, 0, 0);
      }
    }
    if (more) {
      __syncthreads();                          // all waves done with LDS
      *(h8v*)&Ks[krow][kc]     = ka0;
      *(h8v*)&Ks[krow][kc + 8] = ka1;
      *(h8v*)&Vt[vd][vc]       = va0;
      *(h8v*)&Vt[vd][vc + 8]   = va1;
      __syncthreads();                          // next tile ready
    }
  }

  float linv[4];
  #pragma unroll
  for (int r = 0; r < 4; ++r) linv[r] = 1.f / __shfl(l_run, lg * 4 + r);
  h16* Op = ctx + (long)q * BNE + (long)(b * Nn + nt * 64) * Ee + hd * 32;
  #pragma unroll
  for (int r = 0; r < 4; ++r) {
    const long row = w * 16 + lg * 4 + r;
    Op[row * Ee + 0  + lr] = (h16)(cacc[0][r] * linv[r]);
    Op[row * Ee + 16 + lr] = (h16)(cacc[1][r] * linv[r]);
  }
}

// ---------------------------------------------------------------------------
// Launcher. Workspace (halves), ~44 MB with aliasing (same layout as R5).
// ---------------------------------------------------------------------------
extern "C" void kernel_launch(void* const* d_in, const int* in_sizes, int n_in,
                              void* d_out, int out_size, void* d_ws, size_t ws_size,
                              hipStream_t stream)
{
  (void)in_sizes; (void)n_in; (void)out_size; (void)ws_size;
  const float* emb[4] = {(const float*)d_in[0], (const float*)d_in[1],
                         (const float*)d_in[2], (const float*)d_in[3]};
  const float* gamma1 = (const float*)d_in[18];
  const float* gamma2 = (const float*)d_in[20];
  float* out = (float*)d_out;

  h16* hws = (h16*)d_ws;
  h16* embC16 = hws;
  h16* QC16   = hws + 2359296L;
  h16* KC16   = hws + 4718592L;
  h16* VC16   = hws + 7077888L;
  h16* attnR  = hws + 9437184L;
  float* attnC = (float*)attnR;
  h16* WcT  = hws + 17825792L;
  h16* WkvT = WcT + 3145728L;
  h16* WqT  = WkvT + 131072L;
  h16* WoT  = WqT + 262144L;
  float* stats = (float*)(hws + 21626880L);
  float* sums = stats;
  float* Gk   = stats + 8;
  float* km   = Gk + 32768;
  float* Gq   = km + 1024;
  float* qm   = Gq + 131072;
  float* sc2v = qm + 4096;
  // aliases (lifetimes verified against launch order)
  h16* sim16  = QC16;
  h16* KVS16  = embC16;
  h16* Kbuf16 = attnR;
  h16* Vbuf16 = attnR + 2359296L;
  h16* Qbuf16 = attnR + 4718592L;
  h16* vT     = embC16;     // after KV-proj consumes KVS16
  h16* ctx16  = VC16;

  hipMemsetAsync(sums, 0, 8 * sizeof(float), stream);

  {
    WtP wp;
    wp.src[0] = (const float*)d_in[5];  wp.dst[0] = WcT;                 // WqC
    wp.src[1] = (const float*)d_in[6];  wp.dst[1] = WcT + 1048576L;      // WkC
    wp.src[2] = (const float*)d_in[7];  wp.dst[2] = WcT + 2097152L;      // WvC
    wp.src[3] = (const float*)d_in[12]; wp.dst[3] = WkvT;                // Wk
    wp.src[4] = (const float*)d_in[13]; wp.dst[4] = WkvT + 65536L;       // Wv
    for (int i = 0; i < 4; ++i) {
      wp.src[5 + i] = (const float*)d_in[8 + i];  wp.dst[5 + i] = WqT + (long)i * 65536;
      wp.src[9 + i] = (const float*)d_in[14 + i]; wp.dst[9 + i] = WoT + (long)i * 65536;
    }
    wp.embC = (const float*)d_in[4]; wp.dEmbC = embC16;
    wtrans<<<3232, 256, 0, stream>>>(wp);
  }

  // Stage A: [QC|KC|VC]16 = embC16 @ Wc  (2304 x 3072 x 1024), BM=64
  {
    GemmP gp{};
    gp.A[0] = embC16; gp.B[0] = WcT;
    gp.O[0][0] = QC16; gp.O[0][1] = KC16; gp.O[0][2] = VC16;
    mg<64,0,1,0,1,0,0,10><<<dim3(24,36,1), 256, 0, stream>>>(gp, 1024, 1024, 1024, 1024, nullptr);
  }
  // attn_c[b] = QC^T @ KC (1024x1024x576) fp32 + fused stats, BM=64
  {
    GemmP gp{};
    for (int z = 0; z < 4; ++z) {
      gp.A[z] = QC16 + (long)z * 589824; gp.B[z] = KC16 + (long)z * 589824;
      gp.O[z][0] = attnC + (long)z * CCl;
    }
    mg<64,1,0,0,0,0,1,30><<<dim3(8,16,4), 256, 0, stream>>>(gp, 576, 1024, 1024, 1024, sums);
  }
  softmax_c<<<4096, 256, 0, stream>>>(attnC, sums, gamma1, sim16);
  // T_hat[b] = VC @ sim^T -> KV_S layout fp16 (576x1024x1024)
  {
    GemmP gp{};
    for (int z = 0; z < 4; ++z) {
      gp.A[z] = VC16 + (long)z * 589824; gp.B[z] = sim16 + (long)z * CCl;
      gp.O[z][0] = KVS16 + (long)z * 589824;
    }
    mg<64,0,1,0,1,1,0,30><<<dim3(8,9,4), 256, 0, stream>>>(gp, 1024, 1024, 1024, 256, nullptr);
  }
  // K/V projections: (9216 x 512 x 256), BM=64
  {
    GemmP gp{};
    gp.A[0] = KVS16; gp.B[0] = WkvT;
    gp.O[0][0] = Kbuf16; gp.O[0][1] = Vbuf16;
    mg<64,0,1,0,1,0,0,8><<<dim3(4,144,1), 256, 0, stream>>>(gp, 256, 256, 256, 256, nullptr);
  }
  // Q projections: 4 x (2304 x 256 x 256), A fp32
  {
    GemmP gp{};
    for (int z = 0; z < 4; ++z) {
      gp.A32[z] = emb[z]; gp.B[z] = WqT + (long)z * 65536;
      gp.O[z][0] = Qbuf16 + (long)z * 589824;
    }
    mg<64,0,1,1,1,0,0,30><<<dim3(2,36,4), 256, 0, stream>>>(gp, 256, 256, 256, 256, nullptr);
  }
  // V pre-transpose for flash (KVS16 dead -> vT aliases it)
  vtrans<<<dim3(36,32), 256, 0, stream>>>(Vbuf16, vT);
  // analytic inorm scales for stage-2 attention
  gram_all<<<160, 256, 0, stream>>>(Kbuf16, Qbuf16, Gk, km, Gq, qm);
  finalize_scale2<<<128, 256, 0, stream>>>(Gq, Gk, qm, km, gamma2, sc2v);
  // flash attention -> ctx (4,B,N,E)
  flash5<<<1152, 256, 0, stream>>>(Qbuf16, Kbuf16, vT, sc2v, ctx16);
  // output projections: 4 x (2304 x 256 x 256) -> fp32 d_out
  {
    GemmP gp{};
    for (int z = 0; z < 4; ++z) {
      gp.A[z] = ctx16 + (long)z * 589824; gp.B[z] = WoT + (long)z * 65536;
      gp.O[z][0] = out + (long)z * 589824;
    }
    mg<64,0,1,0,0,0,0,30><<<dim3(2,36,4), 256, 0, stream>>>(gp, 256, 256, 256, 256, nullptr);
  }
}

// Round 7
// 354.879 us; speedup vs baseline: 1.4247x; 1.2040x over previous
//
#include <hip/hip_runtime.h>
#include <math.h>

// ---------------------------------------------------------------------------
// UDTransNet fused forward. fp16 MFMA everywhere (fp32 accum), fp16
// intermediates, transposed weights, reg-prefetch double-buffered staging.
// Sizes: B=4, N=576, E=256, C=4E=1024, H=8, dh=32, M=4N=2304.
// ---------------------------------------------------------------------------

namespace {
constexpr int Bq  = 4;
constexpr int Nn  = 576;
constexpr int Ee  = 256;
constexpr int Cc  = 1024;
constexpr int Mm  = 2304;
constexpr long BNE = (long)Bq * Nn * Ee;     // 589824
constexpr long CCl = (long)Cc * Cc;          // 1048576
constexpr float EPSV = 1e-3f;
constexpr float LOG2E = 1.4426950408889634f;
} // namespace

typedef _Float16 h16;
typedef _Float16 h8v __attribute__((ext_vector_type(8)));
typedef _Float16 h4v __attribute__((ext_vector_type(4)));
typedef float    f4v __attribute__((ext_vector_type(4)));

// ---------------------------------------------------------------------------
// wtrans: weights fp32[K][N] -> h16[N][K] (64x64 LDS tiles, chunk-XOR
// swizzle) + straight fp32->fp16 copy of emb_C.
// ---------------------------------------------------------------------------
struct WtP {
  const float* src[13]; h16* dst[13];
  const float* embC; h16* dEmbC;
};

__global__ __launch_bounds__(256) void wtrans(WtP p)
{
  const int bt = blockIdx.x;
  const int t = threadIdx.x;
  if (bt >= 928) {
    const long i4 = ((long)(bt - 928) * 256 + t) * 4;
    const float4 v = *(const float4*)(p.embC + i4);
    h4v o = {(h16)v.x, (h16)v.y, (h16)v.z, (h16)v.w};
    *(h4v*)(p.dEmbC + i4) = o;
    return;
  }
  __shared__ h16 Ls[64][64];
  int mi, tile, Kd, Nd;
  if (bt < 768) { mi = bt >> 8; tile = bt & 255; Kd = 1024; Nd = 1024; }
  else { const int r = bt - 768; mi = 3 + (r >> 4); tile = r & 15; Kd = 256; Nd = 256; }
  const int ntn = Nd >> 6;
  const int tk = tile / ntn, tn = tile % ntn;
  const float* src = p.src[mi] + (long)(tk * 64) * Nd + tn * 64;
  h16* dst = p.dst[mi] + (long)(tn * 64) * Kd + tk * 64;
  #pragma unroll
  for (int it = 0; it < 4; ++it) {
    const int kr = (t >> 4) + it * 16;
    const int c4 = (t & 15) * 4;
    const float4 v = *(const float4*)(src + (long)kr * Nd + c4);
    const float vv[4] = {v.x, v.y, v.z, v.w};
    #pragma unroll
    for (int jj = 0; jj < 4; ++jj) {
      const int n = c4 + jj;
      Ls[n][(((kr >> 3) ^ ((n >> 3) & 7)) << 3) | (kr & 7)] = (h16)vv[jj];
    }
  }
  __syncthreads();
  #pragma unroll
  for (int it = 0; it < 2; ++it) {
    const int n = t >> 2;
    const int k8 = (t & 3) + it * 4;
    const h8v o = *(const h8v*)&Ls[n][(k8 ^ ((n >> 3) & 7)) << 3];
    *(h8v*)(dst + (long)n * Kd + k8 * 8) = o;
  }
}

// ---------------------------------------------------------------------------
// vtrans: Vbuf [b][2304][256] -> vT [b*8+h][32][2304].
// ---------------------------------------------------------------------------
__global__ __launch_bounds__(256) void vtrans(
    const h16* __restrict__ V, h16* __restrict__ vT)
{
  __shared__ h16 Ls[32][64];
  const int kc = blockIdx.x;           // 0..35
  const int bh = blockIdx.y;           // 0..31
  const int b = bh >> 3, h = bh & 7;
  const int t = threadIdx.x;
  const int kv0 = kc * 64;
  {
    const int row = t >> 2, c8 = t & 3;
    const h8v v = *(const h8v*)(V + ((long)b * Mm + kv0 + row) * Ee + h * 32 + c8 * 8);
    #pragma unroll
    for (int e = 0; e < 8; ++e) {
      const int d = c8 * 8 + e;
      Ls[d][(((row >> 3) ^ ((d >> 3) & 7)) << 3) | (row & 7)] = v[e];
    }
  }
  __syncthreads();
  {
    const int d = t >> 3, j8 = t & 7;
    const h8v o = *(const h8v*)&Ls[d][(j8 ^ ((d >> 3) & 7)) << 3];
    *(h8v*)(vT + ((long)bh * 32 + d) * Mm + kv0 + j8 * 8) = o;
  }
}

// ---------------------------------------------------------------------------
// fp16 MFMA GEMM with register-prefetch double buffering (T14 async split).
// BN=128, BK=64, 256 threads. LDS pitch 64, chunk-XOR swizzle.
// ---------------------------------------------------------------------------
struct GemmP {
  const h16* A[4]; const h16* B[4]; void* O[4][3]; const float* A32[4];
};

template <int BM, int TA, int TB, int AF32, int OUT16, int RM, int STATS, int OSHIFT>
__global__ __launch_bounds__(256) void mg(GemmP p, int K, int lda, int ldb,
                                          int ldc, float* stats)
{
  __shared__ h16 As[BM][64];
  __shared__ h16 Bs[128][64];
  const int z = blockIdx.z;
  const h16* A = p.A[z]; const h16* B = p.B[z]; const float* A32 = p.A32[z];
  const int n0 = blockIdx.x * 128, m0 = blockIdx.y * BM;
  const int t = threadIdx.x, w = t >> 6, lg = (t >> 4) & 3, lr = t & 15;
  constexpr int MF = 4, NF = (BM == 128 ? 4 : 2);
  const int wm = (BM == 128) ? (w & 1) * 64 : 0;
  const int wn = (BM == 128) ? (w >> 1) * 64 : w * 32;

  h8v   rA[AF32 ? 1 : BM / 32];
  float4 rF[AF32 ? BM / 16 : 1];
  h8v   rB[4];

  auto LOAD = [&](int kt) {
    if constexpr (AF32) {
      #pragma unroll
      for (int it = 0; it < BM / 16; ++it) {
        const int f = t + it * 256, row = f >> 4, c4 = f & 15;
        rF[it] = *(const float4*)(A32 + (long)(m0 + row) * lda + kt + c4 * 4);
      }
    } else if constexpr (TA == 0) {
      #pragma unroll
      for (int it = 0; it < BM / 32; ++it) {
        const int f = t + it * 256, row = f >> 3, c8 = f & 7;
        rA[it] = *(const h8v*)(A + (long)(m0 + row) * lda + kt + c8 * 8);
      }
    } else {
      #pragma unroll
      for (int it = 0; it < BM / 32; ++it) {
        const int f = t + it * 256;
        const int kr = (BM == 128) ? (f >> 4) : (f >> 3);
        const int mc = (BM == 128) ? (f & 15) : (f & 7);
        rA[it] = *(const h8v*)(A + (long)(kt + kr) * lda + m0 + mc * 8);
      }
    }
    if constexpr (TB == 0) {
      #pragma unroll
      for (int it = 0; it < 4; ++it) {
        const int f = t + it * 256, kr = f >> 4, nc = f & 15;
        rB[it] = *(const h8v*)(B + (long)(kt + kr) * ldb + n0 + nc * 8);
      }
    } else {
      #pragma unroll
      for (int it = 0; it < 4; ++it) {
        const int f = t + it * 256, row = f >> 3, c8 = f & 7;
        rB[it] = *(const h8v*)(B + (long)(n0 + row) * ldb + kt + c8 * 8);
      }
    }
  };

  auto STORE = [&]() {
    if constexpr (AF32) {
      #pragma unroll
      for (int it = 0; it < BM / 16; ++it) {
        const int f = t + it * 256, row = f >> 4, c4 = f & 15;
        const float4 v = rF[it];
        h4v o = {(h16)v.x, (h16)v.y, (h16)v.z, (h16)v.w};
        const int col = ((((c4 >> 1) ^ ((row >> 3) & 7)) << 3) | ((c4 & 1) << 2));
        *(h4v*)&As[row][col] = o;
      }
    } else if constexpr (TA == 0) {
      #pragma unroll
      for (int it = 0; it < BM / 32; ++it) {
        const int f = t + it * 256, row = f >> 3, c8 = f & 7;
        *(h8v*)&As[row][(c8 ^ ((row >> 3) & 7)) << 3] = rA[it];
      }
    } else {
      #pragma unroll
      for (int it = 0; it < BM / 32; ++it) {
        const int f = t + it * 256;
        const int kr = (BM == 128) ? (f >> 4) : (f >> 3);
        const int mc = (BM == 128) ? (f & 15) : (f & 7);
        const int colb = (((kr >> 3) ^ (mc & 7)) << 3) | (kr & 7);
        #pragma unroll
        for (int e = 0; e < 8; ++e) As[mc * 8 + e][colb] = rA[it][e];
      }
    }
    if constexpr (TB == 0) {
      #pragma unroll
      for (int it = 0; it < 4; ++it) {
        const int f = t + it * 256, kr = f >> 4, nc = f & 15;
        const int colb = (((kr >> 3) ^ (nc & 7)) << 3) | (kr & 7);
        #pragma unroll
        for (int e = 0; e < 8; ++e) Bs[nc * 8 + e][colb] = rB[it][e];
      }
    } else {
      #pragma unroll
      for (int it = 0; it < 4; ++it) {
        const int f = t + it * 256, row = f >> 3, c8 = f & 7;
        *(h8v*)&Bs[row][(c8 ^ ((row >> 3) & 7)) << 3] = rB[it];
      }
    }
  };

  f4v acc[MF][NF];
  #pragma unroll
  for (int i = 0; i < MF; ++i)
    #pragma unroll
    for (int j = 0; j < NF; ++j) acc[i][j] = (f4v){0.f, 0.f, 0.f, 0.f};

  LOAD(0);
  STORE();
  __syncthreads();

  for (int kt = 0;;) {
    const int ktn = kt + 64;
    const bool more = ktn < K;
    if (more) LOAD(ktn);                       // overlap with MFMA below

    #pragma unroll
    for (int ks = 0; ks < 2; ++ks) {
      h8v af[MF], bf[NF];
      #pragma unroll
      for (int mf = 0; mf < MF; ++mf) {
        const int row = wm + mf * 16 + lr;
        af[mf] = *(const h8v*)&As[row][((ks * 4 + lg) ^ ((row >> 3) & 7)) << 3];
      }
      #pragma unroll
      for (int nf = 0; nf < NF; ++nf) {
        const int row = wn + nf * 16 + lr;
        bf[nf] = *(const h8v*)&Bs[row][((ks * 4 + lg) ^ ((row >> 3) & 7)) << 3];
      }
      #pragma unroll
      for (int mf = 0; mf < MF; ++mf)
        #pragma unroll
        for (int nf = 0; nf < NF; ++nf)
          acc[mf][nf] = __builtin_amdgcn_mfma_f32_16x16x32_f16(af[mf], bf[nf], acc[mf][nf], 0, 0, 0);
    }
    if (!more) break;
    __syncthreads();                           // all LDS reads done
    STORE();
    __syncthreads();                           // LDS ready
    kt = ktn;
  }

  float s1 = 0.f, s2 = 0.f;
  #pragma unroll
  for (int mf = 0; mf < MF; ++mf)
    #pragma unroll
    for (int nf = 0; nf < NF; ++nf)
      #pragma unroll
      for (int r = 0; r < 4; ++r) {
        const int m = m0 + wm + mf * 16 + lg * 4 + r;
        const int n = n0 + wn + nf * 16 + lr;
        const float v = acc[mf][nf][r];
        if (STATS) { s1 += v; s2 += v * v; }
        if (RM) {
          ((h16*)p.O[z][0])[((long)(n >> 8) * Nn + m) * Ee + (n & 255)] = (h16)v;
        } else {
          const int chunk = n >> OSHIFT;
          const int col = n & ((1 << OSHIFT) - 1);
          if (OUT16) ((h16*)p.O[z][chunk])[(long)m * ldc + col] = (h16)v;
          else       ((float*)p.O[z][chunk])[(long)m * ldc + col] = v;
        }
      }
  if (STATS) {
    #pragma unroll
    for (int o = 1; o < 64; o <<= 1) { s1 += __shfl_xor(s1, o); s2 += __shfl_xor(s2, o); }
    if ((t & 63) == 0) { atomicAdd(&stats[z * 2], s1); atomicAdd(&stats[z * 2 + 1], s2); }
  }
}

// ---------------------------------------------------------------------------
// sim_c = softmax(attn_c * gamma1*rsqrt(var+eps), axis=-1) -> fp16.
// ---------------------------------------------------------------------------
__global__ __launch_bounds__(256) void softmax_c(
    const float* __restrict__ AC, const float* __restrict__ sums,
    const float* __restrict__ g1, h16* __restrict__ sim)
{
  __shared__ float red[256];
  const long r = blockIdx.x;
  const int b = (int)(r >> 10);
  const float* p = AC + r * Cc;
  const float invn = 1.f / (float)CCl;
  const float mean = sums[b * 2] * invn;
  const float var  = sums[b * 2 + 1] * invn - mean * mean;
  const float scb  = g1[0] * rsqrtf(var + EPSV);
  const int t = threadIdx.x;
  float4 v = ((const float4*)p)[t];
  v.x *= scb; v.y *= scb; v.z *= scb; v.w *= scb;
  float mx = fmaxf(fmaxf(v.x, v.y), fmaxf(v.z, v.w));
  red[t] = mx; __syncthreads();
  for (int s = 128; s > 0; s >>= 1) { if (t < s) red[t] = fmaxf(red[t], red[t + s]); __syncthreads(); }
  mx = red[0]; __syncthreads();
  v.x = __expf(v.x - mx); v.y = __expf(v.y - mx);
  v.z = __expf(v.z - mx); v.w = __expf(v.w - mx);
  red[t] = v.x + v.y + v.z + v.w; __syncthreads();
  for (int s = 128; s > 0; s >>= 1) { if (t < s) red[t] += red[t + s]; __syncthreads(); }
  const float inv = 1.f / red[0];
  h4v o = {(h16)(v.x * inv), (h16)(v.y * inv), (h16)(v.z * inv), (h16)(v.w * inv)};
  *(h4v*)&sim[r * Cc + t * 4] = o;
}

// ---------------------------------------------------------------------------
// gram2: MFMA-based 32x32 Gram + column sums for the analytic stage-2 scale.
// G = X^T X via mfma_f32_16x16x32_f16: A-frag[d][k] = X[k][d] (d=lr,
// k=lg*8+j), B-frag identical for the other 16-col window; 4 MFMA/k-step.
// 192 blocks x 4 waves: blk<64 -> K-side (bh=blk>>1, half-slab of 1152 rows,
// atomicAdd into pre-zeroed Gk/km); blk>=64 -> Q-side (i=blk-64, 576 rows,
// direct store). Col sums folded in (per-lane partial + 2 shuffles).
// ---------------------------------------------------------------------------
__global__ __launch_bounds__(256) void gram2(
    const h16* __restrict__ Kb, const h16* __restrict__ Qb,
    float* __restrict__ Gk, float* __restrict__ km,
    float* __restrict__ Gq, float* __restrict__ qm)
{
  __shared__ float Gw[4][1024];
  __shared__ float csw[4][32];
  const int blk = blockIdx.x;
  const int t = threadIdx.x, w = t >> 6, lg = (t >> 4) & 3, lr = t & 15;

  const h16* slab; float* gout; float* msum;
  int nsteps; bool katomic;
  if (blk < 64) {
    const int bh = blk >> 1, chunk = blk & 1;
    slab = Kb + ((long)(bh >> 3) * Mm + chunk * 1152) * Ee + (bh & 7) * 32;
    gout = Gk + (long)bh * 1024; msum = km + bh * 32;
    nsteps = 36; katomic = true;
  } else {
    const int i = blk - 64, qq = i >> 5, b = (i >> 3) & 3, hd = i & 7;
    slab = Qb + (long)qq * BNE + ((long)b * Nn) * Ee + hd * 32;
    gout = Gq + (long)i * 1024; msum = qm + i * 32;
    nsteps = 18; katomic = false;
  }

  f4v acc[2][2];
  #pragma unroll
  for (int i = 0; i < 2; ++i)
    #pragma unroll
    for (int j = 0; j < 2; ++j) acc[i][j] = (f4v){0.f, 0.f, 0.f, 0.f};
  float cs0 = 0.f, cs1 = 0.f;

  for (int s = w; s < nsteps; s += 4) {
    const long rbase = (long)s * 32 + lg * 8;
    h8v f0, f1;
    #pragma unroll
    for (int j = 0; j < 8; ++j) {
      const h16* rp = slab + (rbase + j) * Ee;
      f0[j] = rp[lr];
      f1[j] = rp[lr + 16];
      cs0 += (float)f0[j];
      cs1 += (float)f1[j];
    }
    acc[0][0] = __builtin_amdgcn_mfma_f32_16x16x32_f16(f0, f0, acc[0][0], 0, 0, 0);
    acc[0][1] = __builtin_amdgcn_mfma_f32_16x16x32_f16(f0, f1, acc[0][1], 0, 0, 0);
    acc[1][0] = __builtin_amdgcn_mfma_f32_16x16x32_f16(f1, f0, acc[1][0], 0, 0, 0);
    acc[1][1] = __builtin_amdgcn_mfma_f32_16x16x32_f16(f1, f1, acc[1][1], 0, 0, 0);
  }

  cs0 += __shfl_xor(cs0, 16); cs0 += __shfl_xor(cs0, 32);
  cs1 += __shfl_xor(cs1, 16); cs1 += __shfl_xor(cs1, 32);
  if (lg == 0) { csw[w][lr] = cs0; csw[w][lr + 16] = cs1; }

  #pragma unroll
  for (int i = 0; i < 2; ++i)
    #pragma unroll
    for (int j = 0; j < 2; ++j)
      #pragma unroll
      for (int r = 0; r < 4; ++r) {
        const int d = i * 16 + lg * 4 + r;
        const int e = j * 16 + lr;
        Gw[w][d * 32 + e] = acc[i][j][r];
      }
  __syncthreads();

  #pragma unroll
  for (int u = 0; u < 4; ++u) {
    const int flat = t + u * 256;
    const float v = Gw[0][flat] + Gw[1][flat] + Gw[2][flat] + Gw[3][flat];
    if (katomic) atomicAdd(&gout[flat], v);
    else gout[flat] = v;
  }
  if (t < 32) {
    const float m = csw[0][t] + csw[1][t] + csw[2][t] + csw[3][t];
    if (katomic) atomicAdd(&msum[t], m);
    else msum[t] = m;
  }
}

__global__ __launch_bounds__(256) void finalize_scale2(
    const float* __restrict__ Gq, const float* __restrict__ Gk,
    const float* __restrict__ qm, const float* __restrict__ km,
    const float* __restrict__ g2, float* __restrict__ sc2)
{
  __shared__ float red[4];
  const int i = blockIdx.x;            // 0..127 (q,b,h)
  const int kb = i & 31;
  const int t = threadIdx.x;
  const float4 a = *(const float4*)(Gq + (long)i * 1024 + t * 4);
  const float4 b = *(const float4*)(Gk + (long)kb * 1024 + t * 4);
  float s = a.x * b.x + a.y * b.y + a.z * b.z + a.w * b.w;
  #pragma unroll
  for (int o = 1; o < 64; o <<= 1) s += __shfl_xor(s, o);
  if ((t & 63) == 0) red[t >> 6] = s;
  float mu = 0.f;
  if (t < 32) mu = qm[i * 32 + t] * km[kb * 32 + t];
  #pragma unroll
  for (int o = 1; o < 32; o <<= 1) mu += __shfl_xor(mu, o);
  __syncthreads();
  if (t == 0) {
    const float tot = red[0] + red[1] + red[2] + red[3];
    const float inv = 1.f / ((float)Nn * (float)Mm);
    const float ex2 = tot * inv;
    const float m1  = mu * inv;
    sc2[i] = g2[i & 7] * rsqrtf(ex2 - m1 * m1 + EPSV) * LOG2E;  // exp2 domain
  }
}

// ---------------------------------------------------------------------------
// flash5: swapped-QK^T MFMA flash attention, K+Vt staged in LDS, register
// prefetch double buffering. Odd pitches -> conflict-free. XCD-swizzled.
// ---------------------------------------------------------------------------
__global__ __launch_bounds__(256) void flash5(
    const h16* __restrict__ Qb, const h16* __restrict__ Kb,
    const h16* __restrict__ vT, const float* __restrict__ sc2,
    h16* __restrict__ ctx)
{
  __shared__ h16 Ks[128][40];
  __shared__ h16 Vt[32][136];
  __shared__ h16 Ps[64][136];
  const int pidx = blockIdx.x;
  const int x = pidx & 7, rest = pidx >> 3;
  const int j = rest % 36, g = rest / 36;
  const int bh = g * 8 + x, b = bh >> 3, hd = bh & 7;
  const int nt = j % 9, q = j / 9;
  const int t = threadIdx.x, w = t >> 6, lg = (t >> 4) & 3, lr = t & 15;
  const float sc = sc2[(q << 5) + bh];

  const h16* Qp = Qb + (long)q * BNE + (long)(b * Nn + nt * 64) * Ee + hd * 32;
  const h16* Kp = Kb + ((long)b * Mm) * Ee + hd * 32;
  const h16* Vp = vT + (long)bh * (32L * Mm);

  const h8v qf = *(const h8v*)(Qp + (long)(w * 16 + lr) * Ee + lg * 8);

  const int krow = t >> 1, kc = (t & 1) * 16;   // K staging: 2 h8v / thread
  const int vd   = t >> 3, vc = (t & 7) * 16;   // Vt staging: 2 h8v / thread

  h8v ka0, ka1, va0, va1;
  ka0 = *(const h8v*)(Kp + (long)krow * Ee + kc);
  ka1 = *(const h8v*)(Kp + (long)krow * Ee + kc + 8);
  va0 = *(const h8v*)(Vp + (long)vd * Mm + vc);
  va1 = *(const h8v*)(Vp + (long)vd * Mm + vc + 8);
  *(h8v*)&Ks[krow][kc]     = ka0;
  *(h8v*)&Ks[krow][kc + 8] = ka1;
  *(h8v*)&Vt[vd][vc]       = va0;
  *(h8v*)&Vt[vd][vc + 8]   = va1;

  float m_run = -3e38f, l_run = 0.f;
  f4v cacc[2];
  cacc[0] = (f4v){0.f, 0.f, 0.f, 0.f};
  cacc[1] = (f4v){0.f, 0.f, 0.f, 0.f};
  __syncthreads();

  for (int mt = 0; mt < 18; ++mt) {
    const bool more = mt < 17;
    if (more) {                                 // issue next-tile loads early
      const long ko = (long)((mt + 1) * 128 + krow) * Ee + kc;
      ka0 = *(const h8v*)(Kp + ko);
      ka1 = *(const h8v*)(Kp + ko + 8);
      const long vo = (long)vd * Mm + (mt + 1) * 128 + vc;
      va0 = *(const h8v*)(Vp + vo);
      va1 = *(const h8v*)(Vp + vo + 8);
    }

    // S = K Q^T from LDS (lane owns q-row lr, 32 kv logits)
    f4v s[8];
    #pragma unroll
    for (int nf = 0; nf < 8; ++nf) {
      const h8v kf = *(const h8v*)&Ks[nf * 16 + lr][lg * 8];
      s[nf] = __builtin_amdgcn_mfma_f32_16x16x32_f16(kf, qf, (f4v){0.f, 0.f, 0.f, 0.f}, 0, 0, 0);
    }
    // in-lane online softmax (raw-domain max; sc > 0)
    float mx = -3e38f;
    #pragma unroll
    for (int nf = 0; nf < 8; ++nf)
      #pragma unroll
      for (int r = 0; r < 4; ++r) mx = fmaxf(mx, s[nf][r]);
    mx = fmaxf(mx, __shfl_xor(mx, 16));
    mx = fmaxf(mx, __shfl_xor(mx, 32));
    const float mnew = fmaxf(m_run, mx * sc);
    const float corr = __builtin_amdgcn_exp2f(m_run - mnew);
    float rs = 0.f;
    #pragma unroll
    for (int nf = 0; nf < 8; ++nf)
      #pragma unroll
      for (int r = 0; r < 4; ++r) {
        const float pv = __builtin_amdgcn_exp2f(fmaf(s[nf][r], sc, -mnew));
        s[nf][r] = pv; rs += pv;
      }
    rs += __shfl_xor(rs, 16);
    rs += __shfl_xor(rs, 32);
    l_run = l_run * corr + rs;
    m_run = mnew;
    #pragma unroll
    for (int r = 0; r < 4; ++r) {
      const float cr = __shfl(corr, lg * 4 + r);
      cacc[0][r] *= cr; cacc[1][r] *= cr;
    }
    // P -> LDS (wave-local rows; no barrier)
    #pragma unroll
    for (int nf = 0; nf < 8; ++nf) {
      h4v pk = {(h16)s[nf][0], (h16)s[nf][1], (h16)s[nf][2], (h16)s[nf][3]};
      *(h4v*)&Ps[w * 16 + lr][nf * 16 + lg * 4] = pk;
    }
    // ctx += P V from LDS
    #pragma unroll
    for (int ks = 0; ks < 4; ++ks) {
      const h8v pf = *(const h8v*)&Ps[w * 16 + lr][ks * 32 + lg * 8];
      #pragma unroll
      for (int df = 0; df < 2; ++df) {
        const h8v vf = *(const h8v*)&Vt[df * 16 + lr][ks * 32 + lg * 8];
        cacc[df] = __builtin_amdgcn_mfma_f32_16x16x32_f16(pf, vf, cacc[df], 0, 0, 0);
      }
    }
    if (more) {
      __syncthreads();                          // all waves done with LDS
      *(h8v*)&Ks[krow][kc]     = ka0;
      *(h8v*)&Ks[krow][kc + 8] = ka1;
      *(h8v*)&Vt[vd][vc]       = va0;
      *(h8v*)&Vt[vd][vc + 8]   = va1;
      __syncthreads();                          // next tile ready
    }
  }

  float linv[4];
  #pragma unroll
  for (int r = 0; r < 4; ++r) linv[r] = 1.f / __shfl(l_run, lg * 4 + r);
  h16* Op = ctx + (long)q * BNE + (long)(b * Nn + nt * 64) * Ee + hd * 32;
  #pragma unroll
  for (int r = 0; r < 4; ++r) {
    const long row = w * 16 + lg * 4 + r;
    Op[row * Ee + 0  + lr] = (h16)(cacc[0][r] * linv[r]);
    Op[row * Ee + 16 + lr] = (h16)(cacc[1][r] * linv[r]);
  }
}

// ---------------------------------------------------------------------------
// Launcher. Workspace (halves), ~44 MB with aliasing (same layout as R6).
// ---------------------------------------------------------------------------
extern "C" void kernel_launch(void* const* d_in, const int* in_sizes, int n_in,
                              void* d_out, int out_size, void* d_ws, size_t ws_size,
                              hipStream_t stream)
{
  (void)in_sizes; (void)n_in; (void)out_size; (void)ws_size;
  const float* emb[4] = {(const float*)d_in[0], (const float*)d_in[1],
                         (const float*)d_in[2], (const float*)d_in[3]};
  const float* gamma1 = (const float*)d_in[18];
  const float* gamma2 = (const float*)d_in[20];
  float* out = (float*)d_out;

  h16* hws = (h16*)d_ws;
  h16* embC16 = hws;
  h16* QC16   = hws + 2359296L;
  h16* KC16   = hws + 4718592L;
  h16* VC16   = hws + 7077888L;
  h16* attnR  = hws + 9437184L;
  float* attnC = (float*)attnR;
  h16* WcT  = hws + 17825792L;
  h16* WkvT = WcT + 3145728L;
  h16* WqT  = WkvT + 131072L;
  h16* WoT  = WqT + 262144L;
  float* stats = (float*)(hws + 21626880L);
  float* sums = stats;
  float* Gk   = stats + 8;
  float* km   = Gk + 32768;
  float* Gq   = km + 1024;
  float* qm   = Gq + 131072;
  float* sc2v = qm + 4096;
  // aliases (lifetimes verified against launch order)
  h16* sim16  = QC16;
  h16* KVS16  = embC16;
  h16* Kbuf16 = attnR;
  h16* Vbuf16 = attnR + 2359296L;
  h16* Qbuf16 = attnR + 4718592L;
  h16* vT     = embC16;     // after KV-proj consumes KVS16
  h16* ctx16  = VC16;

  // zero sums + Gk + km (gram2 K-side accumulates via atomics)
  hipMemsetAsync(sums, 0, (8 + 32768 + 1024) * sizeof(float), stream);

  {
    WtP wp;
    wp.src[0] = (const float*)d_in[5];  wp.dst[0] = WcT;                 // WqC
    wp.src[1] = (const float*)d_in[6];  wp.dst[1] = WcT + 1048576L;      // WkC
    wp.src[2] = (const float*)d_in[7];  wp.dst[2] = WcT + 2097152L;      // WvC
    wp.src[3] = (const float*)d_in[12]; wp.dst[3] = WkvT;                // Wk
    wp.src[4] = (const float*)d_in[13]; wp.dst[4] = WkvT + 65536L;       // Wv
    for (int i = 0; i < 4; ++i) {
      wp.src[5 + i] = (const float*)d_in[8 + i];  wp.dst[5 + i] = WqT + (long)i * 65536;
      wp.src[9 + i] = (const float*)d_in[14 + i]; wp.dst[9 + i] = WoT + (long)i * 65536;
    }
    wp.embC = (const float*)d_in[4]; wp.dEmbC = embC16;
    wtrans<<<3232, 256, 0, stream>>>(wp);
  }

  // Stage A: [QC|KC|VC]16 = embC16 @ Wc  (2304 x 3072 x 1024), BM=64
  {
    GemmP gp{};
    gp.A[0] = embC16; gp.B[0] = WcT;
    gp.O[0][0] = QC16; gp.O[0][1] = KC16; gp.O[0][2] = VC16;
    mg<64,0,1,0,1,0,0,10><<<dim3(24,36,1), 256, 0, stream>>>(gp, 1024, 1024, 1024, 1024, nullptr);
  }
  // attn_c[b] = QC^T @ KC (1024x1024x576) fp32 + fused stats, BM=64
  {
    GemmP gp{};
    for (int z = 0; z < 4; ++z) {
      gp.A[z] = QC16 + (long)z * 589824; gp.B[z] = KC16 + (long)z * 589824;
      gp.O[z][0] = attnC + (long)z * CCl;
    }
    mg<64,1,0,0,0,0,1,30><<<dim3(8,16,4), 256, 0, stream>>>(gp, 576, 1024, 1024, 1024, sums);
  }
  softmax_c<<<4096, 256, 0, stream>>>(attnC, sums, gamma1, sim16);
  // T_hat[b] = VC @ sim^T -> KV_S layout fp16 (576x1024x1024)
  {
    GemmP gp{};
    for (int z = 0; z < 4; ++z) {
      gp.A[z] = VC16 + (long)z * 589824; gp.B[z] = sim16 + (long)z * CCl;
      gp.O[z][0] = KVS16 + (long)z * 589824;
    }
    mg<64,0,1,0,1,1,0,30><<<dim3(8,9,4), 256, 0, stream>>>(gp, 1024, 1024, 1024, 256, nullptr);
  }
  // K/V projections: (9216 x 512 x 256), BM=64
  {
    GemmP gp{};
    gp.A[0] = KVS16; gp.B[0] = WkvT;
    gp.O[0][0] = Kbuf16; gp.O[0][1] = Vbuf16;
    mg<64,0,1,0,1,0,0,8><<<dim3(4,144,1), 256, 0, stream>>>(gp, 256, 256, 256, 256, nullptr);
  }
  // Q projections: 4 x (2304 x 256 x 256), A fp32
  {
    GemmP gp{};
    for (int z = 0; z < 4; ++z) {
      gp.A32[z] = emb[z]; gp.B[z] = WqT + (long)z * 65536;
      gp.O[z][0] = Qbuf16 + (long)z * 589824;
    }
    mg<64,0,1,1,1,0,0,30><<<dim3(2,36,4), 256, 0, stream>>>(gp, 256, 256, 256, 256, nullptr);
  }
  // V pre-transpose for flash (KVS16 dead -> vT aliases it)
  vtrans<<<dim3(36,32), 256, 0, stream>>>(Vbuf16, vT);
  // analytic inorm scales for stage-2 attention (MFMA gram)
  gram2<<<192, 256, 0, stream>>>(Kbuf16, Qbuf16, Gk, km, Gq, qm);
  finalize_scale2<<<128, 256, 0, stream>>>(Gq, Gk, qm, km, gamma2, sc2v);
  // flash attention -> ctx (4,B,N,E)
  flash5<<<1152, 256, 0, stream>>>(Qbuf16, Kbuf16, vT, sc2v, ctx16);
  // output projections: 4 x (2304 x 256 x 256) -> fp32 d_out
  {
    GemmP gp{};
    for (int z = 0; z < 4; ++z) {
      gp.A[z] = ctx16 + (long)z * 589824; gp.B[z] = WoT + (long)z * 65536;
      gp.O[z][0] = out + (long)z * 589824;
    }
    mg<64,0,1,0,0,0,0,30><<<dim3(2,36,4), 256, 0, stream>>>(gp, 256, 256, 256, 256, nullptr);
  }
}

// Round 8
// 348.743 us; speedup vs baseline: 1.4497x; 1.0176x over previous
//
#include <hip/hip_runtime.h>
#include <math.h>

// ---------------------------------------------------------------------------
// UDTransNet fused forward. fp16 MFMA everywhere (fp32 accum), fp16
// intermediates, transposed weights, reg-prefetch double-buffered staging.
// Sizes: B=4, N=576, E=256, C=4E=1024, H=8, dh=32, M=4N=2304.
// ---------------------------------------------------------------------------

namespace {
constexpr int Bq  = 4;
constexpr int Nn  = 576;
constexpr int Ee  = 256;
constexpr int Cc  = 1024;
constexpr int Mm  = 2304;
constexpr long BNE = (long)Bq * Nn * Ee;     // 589824
constexpr long CCl = (long)Cc * Cc;          // 1048576
constexpr float EPSV = 1e-3f;
constexpr float LOG2E = 1.4426950408889634f;
} // namespace

typedef _Float16 h16;
typedef _Float16 h8v __attribute__((ext_vector_type(8)));
typedef _Float16 h4v __attribute__((ext_vector_type(4)));
typedef float    f4v __attribute__((ext_vector_type(4)));

// ---------------------------------------------------------------------------
// wtrans: weights fp32[K][N] -> h16[N][K] (64x64 LDS tiles, chunk-XOR
// swizzle) + straight fp32->fp16 copy of emb_C.
// ---------------------------------------------------------------------------
struct WtP {
  const float* src[13]; h16* dst[13];
  const float* embC; h16* dEmbC;
};

__global__ __launch_bounds__(256) void wtrans(WtP p)
{
  const int bt = blockIdx.x;
  const int t = threadIdx.x;
  if (bt >= 928) {
    const long i4 = ((long)(bt - 928) * 256 + t) * 4;
    const float4 v = *(const float4*)(p.embC + i4);
    h4v o = {(h16)v.x, (h16)v.y, (h16)v.z, (h16)v.w};
    *(h4v*)(p.dEmbC + i4) = o;
    return;
  }
  __shared__ h16 Ls[64][64];
  int mi, tile, Kd, Nd;
  if (bt < 768) { mi = bt >> 8; tile = bt & 255; Kd = 1024; Nd = 1024; }
  else { const int r = bt - 768; mi = 3 + (r >> 4); tile = r & 15; Kd = 256; Nd = 256; }
  const int ntn = Nd >> 6;
  const int tk = tile / ntn, tn = tile % ntn;
  const float* src = p.src[mi] + (long)(tk * 64) * Nd + tn * 64;
  h16* dst = p.dst[mi] + (long)(tn * 64) * Kd + tk * 64;
  #pragma unroll
  for (int it = 0; it < 4; ++it) {
    const int kr = (t >> 4) + it * 16;
    const int c4 = (t & 15) * 4;
    const float4 v = *(const float4*)(src + (long)kr * Nd + c4);
    const float vv[4] = {v.x, v.y, v.z, v.w};
    #pragma unroll
    for (int jj = 0; jj < 4; ++jj) {
      const int n = c4 + jj;
      Ls[n][(((kr >> 3) ^ ((n >> 3) & 7)) << 3) | (kr & 7)] = (h16)vv[jj];
    }
  }
  __syncthreads();
  #pragma unroll
  for (int it = 0; it < 2; ++it) {
    const int n = t >> 2;
    const int k8 = (t & 3) + it * 4;
    const h8v o = *(const h8v*)&Ls[n][(k8 ^ ((n >> 3) & 7)) << 3];
    *(h8v*)(dst + (long)n * Kd + k8 * 8) = o;
  }
}

// ---------------------------------------------------------------------------
// vtrans: Vbuf [b][2304][256] -> vT [b*8+h][32][2304].
// ---------------------------------------------------------------------------
__global__ __launch_bounds__(256) void vtrans(
    const h16* __restrict__ V, h16* __restrict__ vT)
{
  __shared__ h16 Ls[32][64];
  const int kc = blockIdx.x;           // 0..35
  const int bh = blockIdx.y;           // 0..31
  const int b = bh >> 3, h = bh & 7;
  const int t = threadIdx.x;
  const int kv0 = kc * 64;
  {
    const int row = t >> 2, c8 = t & 3;
    const h8v v = *(const h8v*)(V + ((long)b * Mm + kv0 + row) * Ee + h * 32 + c8 * 8);
    #pragma unroll
    for (int e = 0; e < 8; ++e) {
      const int d = c8 * 8 + e;
      Ls[d][(((row >> 3) ^ ((d >> 3) & 7)) << 3) | (row & 7)] = v[e];
    }
  }
  __syncthreads();
  {
    const int d = t >> 3, j8 = t & 7;
    const h8v o = *(const h8v*)&Ls[d][(j8 ^ ((d >> 3) & 7)) << 3];
    *(h8v*)(vT + ((long)bh * 32 + d) * Mm + kv0 + j8 * 8) = o;
  }
}

// ---------------------------------------------------------------------------
// fp16 MFMA GEMM with register-prefetch double buffering (T14 async split).
// BN=128, BK=64, 256 threads. LDS pitch 64, chunk-XOR swizzle.
// ---------------------------------------------------------------------------
struct GemmP {
  const h16* A[4]; const h16* B[4]; void* O[4][3]; const float* A32[4];
};

template <int BM, int TA, int TB, int AF32, int OUT16, int RM, int STATS, int OSHIFT>
__global__ __launch_bounds__(256) void mg(GemmP p, int K, int lda, int ldb,
                                          int ldc, float* stats)
{
  __shared__ h16 As[BM][64];
  __shared__ h16 Bs[128][64];
  const int z = blockIdx.z;
  const h16* A = p.A[z]; const h16* B = p.B[z]; const float* A32 = p.A32[z];
  const int n0 = blockIdx.x * 128, m0 = blockIdx.y * BM;
  const int t = threadIdx.x, w = t >> 6, lg = (t >> 4) & 3, lr = t & 15;
  constexpr int MF = 4, NF = (BM == 128 ? 4 : 2);
  const int wm = (BM == 128) ? (w & 1) * 64 : 0;
  const int wn = (BM == 128) ? (w >> 1) * 64 : w * 32;

  h8v   rA[AF32 ? 1 : BM / 32];
  float4 rF[AF32 ? BM / 16 : 1];
  h8v   rB[4];

  auto LOAD = [&](int kt) {
    if constexpr (AF32) {
      #pragma unroll
      for (int it = 0; it < BM / 16; ++it) {
        const int f = t + it * 256, row = f >> 4, c4 = f & 15;
        rF[it] = *(const float4*)(A32 + (long)(m0 + row) * lda + kt + c4 * 4);
      }
    } else if constexpr (TA == 0) {
      #pragma unroll
      for (int it = 0; it < BM / 32; ++it) {
        const int f = t + it * 256, row = f >> 3, c8 = f & 7;
        rA[it] = *(const h8v*)(A + (long)(m0 + row) * lda + kt + c8 * 8);
      }
    } else {
      #pragma unroll
      for (int it = 0; it < BM / 32; ++it) {
        const int f = t + it * 256;
        const int kr = (BM == 128) ? (f >> 4) : (f >> 3);
        const int mc = (BM == 128) ? (f & 15) : (f & 7);
        rA[it] = *(const h8v*)(A + (long)(kt + kr) * lda + m0 + mc * 8);
      }
    }
    if constexpr (TB == 0) {
      #pragma unroll
      for (int it = 0; it < 4; ++it) {
        const int f = t + it * 256, kr = f >> 4, nc = f & 15;
        rB[it] = *(const h8v*)(B + (long)(kt + kr) * ldb + n0 + nc * 8);
      }
    } else {
      #pragma unroll
      for (int it = 0; it < 4; ++it) {
        const int f = t + it * 256, row = f >> 3, c8 = f & 7;
        rB[it] = *(const h8v*)(B + (long)(n0 + row) * ldb + kt + c8 * 8);
      }
    }
  };

  auto STORE = [&]() {
    if constexpr (AF32) {
      #pragma unroll
      for (int it = 0; it < BM / 16; ++it) {
        const int f = t + it * 256, row = f >> 4, c4 = f & 15;
        const float4 v = rF[it];
        h4v o = {(h16)v.x, (h16)v.y, (h16)v.z, (h16)v.w};
        const int col = ((((c4 >> 1) ^ ((row >> 3) & 7)) << 3) | ((c4 & 1) << 2));
        *(h4v*)&As[row][col] = o;
      }
    } else if constexpr (TA == 0) {
      #pragma unroll
      for (int it = 0; it < BM / 32; ++it) {
        const int f = t + it * 256, row = f >> 3, c8 = f & 7;
        *(h8v*)&As[row][(c8 ^ ((row >> 3) & 7)) << 3] = rA[it];
      }
    } else {
      #pragma unroll
      for (int it = 0; it < BM / 32; ++it) {
        const int f = t + it * 256;
        const int kr = (BM == 128) ? (f >> 4) : (f >> 3);
        const int mc = (BM == 128) ? (f & 15) : (f & 7);
        const int colb = (((kr >> 3) ^ (mc & 7)) << 3) | (kr & 7);
        #pragma unroll
        for (int e = 0; e < 8; ++e) As[mc * 8 + e][colb] = rA[it][e];
      }
    }
    if constexpr (TB == 0) {
      #pragma unroll
      for (int it = 0; it < 4; ++it) {
        const int f = t + it * 256, kr = f >> 4, nc = f & 15;
        const int colb = (((kr >> 3) ^ (nc & 7)) << 3) | (kr & 7);
        #pragma unroll
        for (int e = 0; e < 8; ++e) Bs[nc * 8 + e][colb] = rB[it][e];
      }
    } else {
      #pragma unroll
      for (int it = 0; it < 4; ++it) {
        const int f = t + it * 256, row = f >> 3, c8 = f & 7;
        *(h8v*)&Bs[row][(c8 ^ ((row >> 3) & 7)) << 3] = rB[it];
      }
    }
  };

  f4v acc[MF][NF];
  #pragma unroll
  for (int i = 0; i < MF; ++i)
    #pragma unroll
    for (int j = 0; j < NF; ++j) acc[i][j] = (f4v){0.f, 0.f, 0.f, 0.f};

  LOAD(0);
  STORE();
  __syncthreads();

  for (int kt = 0;;) {
    const int ktn = kt + 64;
    const bool more = ktn < K;
    if (more) LOAD(ktn);                       // overlap with MFMA below

    #pragma unroll
    for (int ks = 0; ks < 2; ++ks) {
      h8v af[MF], bf[NF];
      #pragma unroll
      for (int mf = 0; mf < MF; ++mf) {
        const int row = wm + mf * 16 + lr;
        af[mf] = *(const h8v*)&As[row][((ks * 4 + lg) ^ ((row >> 3) & 7)) << 3];
      }
      #pragma unroll
      for (int nf = 0; nf < NF; ++nf) {
        const int row = wn + nf * 16 + lr;
        bf[nf] = *(const h8v*)&Bs[row][((ks * 4 + lg) ^ ((row >> 3) & 7)) << 3];
      }
      #pragma unroll
      for (int mf = 0; mf < MF; ++mf)
        #pragma unroll
        for (int nf = 0; nf < NF; ++nf)
          acc[mf][nf] = __builtin_amdgcn_mfma_f32_16x16x32_f16(af[mf], bf[nf], acc[mf][nf], 0, 0, 0);
    }
    if (!more) break;
    __syncthreads();                           // all LDS reads done
    STORE();
    __syncthreads();                           // LDS ready
    kt = ktn;
  }

  float s1 = 0.f, s2 = 0.f;
  #pragma unroll
  for (int mf = 0; mf < MF; ++mf)
    #pragma unroll
    for (int nf = 0; nf < NF; ++nf)
      #pragma unroll
      for (int r = 0; r < 4; ++r) {
        const int m = m0 + wm + mf * 16 + lg * 4 + r;
        const int n = n0 + wn + nf * 16 + lr;
        const float v = acc[mf][nf][r];
        if (STATS) { s1 += v; s2 += v * v; }
        if (RM) {
          ((h16*)p.O[z][0])[((long)(n >> 8) * Nn + m) * Ee + (n & 255)] = (h16)v;
        } else {
          const int chunk = n >> OSHIFT;
          const int col = n & ((1 << OSHIFT) - 1);
          if (OUT16) ((h16*)p.O[z][chunk])[(long)m * ldc + col] = (h16)v;
          else       ((float*)p.O[z][chunk])[(long)m * ldc + col] = v;
        }
      }
  if (STATS) {
    #pragma unroll
    for (int o = 1; o < 64; o <<= 1) { s1 += __shfl_xor(s1, o); s2 += __shfl_xor(s2, o); }
    if ((t & 63) == 0) { atomicAdd(&stats[z * 2], s1); atomicAdd(&stats[z * 2 + 1], s2); }
  }
}

// ---------------------------------------------------------------------------
// sim_c = softmax(attn_c * gamma1*rsqrt(var+eps), axis=-1) -> fp16.
// ---------------------------------------------------------------------------
__global__ __launch_bounds__(256) void softmax_c(
    const float* __restrict__ AC, const float* __restrict__ sums,
    const float* __restrict__ g1, h16* __restrict__ sim)
{
  __shared__ float red[256];
  const long r = blockIdx.x;
  const int b = (int)(r >> 10);
  const float* p = AC + r * Cc;
  const float invn = 1.f / (float)CCl;
  const float mean = sums[b * 2] * invn;
  const float var  = sums[b * 2 + 1] * invn - mean * mean;
  const float scb  = g1[0] * rsqrtf(var + EPSV);
  const int t = threadIdx.x;
  float4 v = ((const float4*)p)[t];
  v.x *= scb; v.y *= scb; v.z *= scb; v.w *= scb;
  float mx = fmaxf(fmaxf(v.x, v.y), fmaxf(v.z, v.w));
  red[t] = mx; __syncthreads();
  for (int s = 128; s > 0; s >>= 1) { if (t < s) red[t] = fmaxf(red[t], red[t + s]); __syncthreads(); }
  mx = red[0]; __syncthreads();
  v.x = __expf(v.x - mx); v.y = __expf(v.y - mx);
  v.z = __expf(v.z - mx); v.w = __expf(v.w - mx);
  red[t] = v.x + v.y + v.z + v.w; __syncthreads();
  for (int s = 128; s > 0; s >>= 1) { if (t < s) red[t] += red[t + s]; __syncthreads(); }
  const float inv = 1.f / red[0];
  h4v o = {(h16)(v.x * inv), (h16)(v.y * inv), (h16)(v.z * inv), (h16)(v.w * inv)};
  *(h4v*)&sim[r * Cc + t * 4] = o;
}

// ---------------------------------------------------------------------------
// gram2: MFMA-based 32x32 Gram + column sums for the analytic stage-2 scale.
// ---------------------------------------------------------------------------
__global__ __launch_bounds__(256) void gram2(
    const h16* __restrict__ Kb, const h16* __restrict__ Qb,
    float* __restrict__ Gk, float* __restrict__ km,
    float* __restrict__ Gq, float* __restrict__ qm)
{
  __shared__ float Gw[4][1024];
  __shared__ float csw[4][32];
  const int blk = blockIdx.x;
  const int t = threadIdx.x, w = t >> 6, lg = (t >> 4) & 3, lr = t & 15;

  const h16* slab; float* gout; float* msum;
  int nsteps; bool katomic;
  if (blk < 64) {
    const int bh = blk >> 1, chunk = blk & 1;
    slab = Kb + ((long)(bh >> 3) * Mm + chunk * 1152) * Ee + (bh & 7) * 32;
    gout = Gk + (long)bh * 1024; msum = km + bh * 32;
    nsteps = 36; katomic = true;
  } else {
    const int i = blk - 64, qq = i >> 5, b = (i >> 3) & 3, hd = i & 7;
    slab = Qb + (long)qq * BNE + ((long)b * Nn) * Ee + hd * 32;
    gout = Gq + (long)i * 1024; msum = qm + i * 32;
    nsteps = 18; katomic = false;
  }

  f4v acc[2][2];
  #pragma unroll
  for (int i = 0; i < 2; ++i)
    #pragma unroll
    for (int j = 0; j < 2; ++j) acc[i][j] = (f4v){0.f, 0.f, 0.f, 0.f};
  float cs0 = 0.f, cs1 = 0.f;

  for (int s = w; s < nsteps; s += 4) {
    const long rbase = (long)s * 32 + lg * 8;
    h8v f0, f1;
    #pragma unroll
    for (int j = 0; j < 8; ++j) {
      const h16* rp = slab + (rbase + j) * Ee;
      f0[j] = rp[lr];
      f1[j] = rp[lr + 16];
      cs0 += (float)f0[j];
      cs1 += (float)f1[j];
    }
    acc[0][0] = __builtin_amdgcn_mfma_f32_16x16x32_f16(f0, f0, acc[0][0], 0, 0, 0);
    acc[0][1] = __builtin_amdgcn_mfma_f32_16x16x32_f16(f0, f1, acc[0][1], 0, 0, 0);
    acc[1][0] = __builtin_amdgcn_mfma_f32_16x16x32_f16(f1, f0, acc[1][0], 0, 0, 0);
    acc[1][1] = __builtin_amdgcn_mfma_f32_16x16x32_f16(f1, f1, acc[1][1], 0, 0, 0);
  }

  cs0 += __shfl_xor(cs0, 16); cs0 += __shfl_xor(cs0, 32);
  cs1 += __shfl_xor(cs1, 16); cs1 += __shfl_xor(cs1, 32);
  if (lg == 0) { csw[w][lr] = cs0; csw[w][lr + 16] = cs1; }

  #pragma unroll
  for (int i = 0; i < 2; ++i)
    #pragma unroll
    for (int j = 0; j < 2; ++j)
      #pragma unroll
      for (int r = 0; r < 4; ++r) {
        const int d = i * 16 + lg * 4 + r;
        const int e = j * 16 + lr;
        Gw[w][d * 32 + e] = acc[i][j][r];
      }
  __syncthreads();

  #pragma unroll
  for (int u = 0; u < 4; ++u) {
    const int flat = t + u * 256;
    const float v = Gw[0][flat] + Gw[1][flat] + Gw[2][flat] + Gw[3][flat];
    if (katomic) atomicAdd(&gout[flat], v);
    else gout[flat] = v;
  }
  if (t < 32) {
    const float m = csw[0][t] + csw[1][t] + csw[2][t] + csw[3][t];
    if (katomic) atomicAdd(&msum[t], m);
    else msum[t] = m;
  }
}

__global__ __launch_bounds__(256) void finalize_scale2(
    const float* __restrict__ Gq, const float* __restrict__ Gk,
    const float* __restrict__ qm, const float* __restrict__ km,
    const float* __restrict__ g2, float* __restrict__ sc2)
{
  __shared__ float red[4];
  const int i = blockIdx.x;            // 0..127 (q,b,h)
  const int kb = i & 31;
  const int t = threadIdx.x;
  const float4 a = *(const float4*)(Gq + (long)i * 1024 + t * 4);
  const float4 b = *(const float4*)(Gk + (long)kb * 1024 + t * 4);
  float s = a.x * b.x + a.y * b.y + a.z * b.z + a.w * b.w;
  #pragma unroll
  for (int o = 1; o < 64; o <<= 1) s += __shfl_xor(s, o);
  if ((t & 63) == 0) red[t >> 6] = s;
  float mu = 0.f;
  if (t < 32) mu = qm[i * 32 + t] * km[kb * 32 + t];
  #pragma unroll
  for (int o = 1; o < 32; o <<= 1) mu += __shfl_xor(mu, o);
  __syncthreads();
  if (t == 0) {
    const float tot = red[0] + red[1] + red[2] + red[3];
    const float inv = 1.f / ((float)Nn * (float)Mm);
    const float ex2 = tot * inv;
    const float m1  = mu * inv;
    sc2[i] = g2[i & 7] * rsqrtf(ex2 - m1 * m1 + EPSV) * LOG2E;  // exp2 domain
  }
}

// ---------------------------------------------------------------------------
// qscale: fold the exp2-domain logit scale into Q (fp16, in place).
// Runs AFTER gram2/finalize (gram needs unscaled Q).
// ---------------------------------------------------------------------------
__global__ __launch_bounds__(256) void qscale(
    h16* __restrict__ Q, const float* __restrict__ sc2)
{
  const long i8 = ((long)blockIdx.x * 256 + threadIdx.x) * 8;
  h8v v = *(const h8v*)(Q + i8);
  const int q   = (int)(i8 / 589824L);
  const int rem = (int)(i8 - (long)q * 589824L);
  const int b   = rem / 147456;
  const int hd  = (rem & 255) >> 5;
  const float sc = sc2[(q << 5) + b * 8 + hd];
  #pragma unroll
  for (int e = 0; e < 8; ++e) v[e] = (h16)((float)v[e] * sc);
  *(h8v*)(Q + i8) = v;
}

// ---------------------------------------------------------------------------
// flash6: swapped-QK^T MFMA flash attention, fixed-max softmax (m=0; logits
// are inorm-normalized -> |exp2 arg| <~ 12, no overflow risk), Q pre-scaled
// (no per-logit mul), l via ones-MFMA (no VALU adds, no epilogue shuffles).
// K+Vt staged in LDS cooperatively, register-prefetch double buffering.
// Odd pitches -> conflict-free b128. XCD-swizzled grid.
// ---------------------------------------------------------------------------
__global__ __launch_bounds__(256) void flash6(
    const h16* __restrict__ Qb, const h16* __restrict__ Kb,
    const h16* __restrict__ vT, h16* __restrict__ ctx)
{
  __shared__ h16 Ks[128][40];
  __shared__ h16 Vt[32][136];
  __shared__ h16 Ps[64][136];
  const int pidx = blockIdx.x;
  const int x = pidx & 7, rest = pidx >> 3;
  const int j = rest % 36, g = rest / 36;
  const int bh = g * 8 + x, b = bh >> 3, hd = bh & 7;
  const int nt = j % 9, q = j / 9;
  const int t = threadIdx.x, w = t >> 6, lg = (t >> 4) & 3, lr = t & 15;

  const h16* Qp = Qb + (long)q * BNE + (long)(b * Nn + nt * 64) * Ee + hd * 32;
  const h16* Kp = Kb + ((long)b * Mm) * Ee + hd * 32;
  const h16* Vp = vT + (long)bh * (32L * Mm);

  const h8v qf = *(const h8v*)(Qp + (long)(w * 16 + lr) * Ee + lg * 8);
  const h8v ones = {(h16)1.f, (h16)1.f, (h16)1.f, (h16)1.f,
                    (h16)1.f, (h16)1.f, (h16)1.f, (h16)1.f};

  const int krow = t >> 1, kc = (t & 1) * 16;   // K staging: 2 h8v / thread
  const int vd   = t >> 3, vc = (t & 7) * 16;   // Vt staging: 2 h8v / thread

  h8v ka0, ka1, va0, va1;
  ka0 = *(const h8v*)(Kp + (long)krow * Ee + kc);
  ka1 = *(const h8v*)(Kp + (long)krow * Ee + kc + 8);
  va0 = *(const h8v*)(Vp + (long)vd * Mm + vc);
  va1 = *(const h8v*)(Vp + (long)vd * Mm + vc + 8);
  *(h8v*)&Ks[krow][kc]     = ka0;
  *(h8v*)&Ks[krow][kc + 8] = ka1;
  *(h8v*)&Vt[vd][vc]       = va0;
  *(h8v*)&Vt[vd][vc + 8]   = va1;

  f4v cacc[2], lacc;
  cacc[0] = (f4v){0.f, 0.f, 0.f, 0.f};
  cacc[1] = (f4v){0.f, 0.f, 0.f, 0.f};
  lacc    = (f4v){0.f, 0.f, 0.f, 0.f};
  __syncthreads();

  for (int mt = 0; mt < 18; ++mt) {
    const bool more = mt < 17;
    if (more) {                                 // issue next-tile loads early
      const long ko = (long)((mt + 1) * 128 + krow) * Ee + kc;
      ka0 = *(const h8v*)(Kp + ko);
      ka1 = *(const h8v*)(Kp + ko + 8);
      const long vo = (long)vd * Mm + (mt + 1) * 128 + vc;
      va0 = *(const h8v*)(Vp + vo);
      va1 = *(const h8v*)(Vp + vo + 8);
    }

    // S = K Q^T from LDS (lane owns q-row lr, 32 kv logits, exp2 domain)
    f4v s[8];
    #pragma unroll
    for (int nf = 0; nf < 8; ++nf) {
      const h8v kf = *(const h8v*)&Ks[nf * 16 + lr][lg * 8];
      s[nf] = __builtin_amdgcn_mfma_f32_16x16x32_f16(kf, qf, (f4v){0.f, 0.f, 0.f, 0.f}, 0, 0, 0);
    }
    // fixed-max softmax: P = exp2(s) directly; pack to fp16; wave-local LDS
    #pragma unroll
    for (int nf = 0; nf < 8; ++nf) {
      h4v pk = {(h16)__builtin_amdgcn_exp2f(s[nf][0]),
                (h16)__builtin_amdgcn_exp2f(s[nf][1]),
                (h16)__builtin_amdgcn_exp2f(s[nf][2]),
                (h16)__builtin_amdgcn_exp2f(s[nf][3])};
      *(h4v*)&Ps[w * 16 + lr][nf * 16 + lg * 4] = pk;
    }
    // ctx += P V ; l += P 1  (all on the matrix pipe)
    #pragma unroll
    for (int ks = 0; ks < 4; ++ks) {
      const h8v pf = *(const h8v*)&Ps[w * 16 + lr][ks * 32 + lg * 8];
      lacc = __builtin_amdgcn_mfma_f32_16x16x32_f16(pf, ones, lacc, 0, 0, 0);
      #pragma unroll
      for (int df = 0; df < 2; ++df) {
        const h8v vf = *(const h8v*)&Vt[df * 16 + lr][ks * 32 + lg * 8];
        cacc[df] = __builtin_amdgcn_mfma_f32_16x16x32_f16(pf, vf, cacc[df], 0, 0, 0);
      }
    }
    if (more) {
      __syncthreads();                          // all waves done with LDS
      *(h8v*)&Ks[krow][kc]     = ka0;
      *(h8v*)&Ks[krow][kc + 8] = ka1;
      *(h8v*)&Vt[vd][vc]       = va0;
      *(h8v*)&Vt[vd][vc + 8]   = va1;
      __syncthreads();                          // next tile ready
    }
  }

  // lacc[r] = l for row w*16+lg*4+r  (same row layout as cacc -> no shuffles)
  h16* Op = ctx + (long)q * BNE + (long)(b * Nn + nt * 64) * Ee + hd * 32;
  #pragma unroll
  for (int r = 0; r < 4; ++r) {
    const float linv = 1.f / lacc[r];
    const long row = w * 16 + lg * 4 + r;
    Op[row * Ee + 0  + lr] = (h16)(cacc[0][r] * linv);
    Op[row * Ee + 16 + lr] = (h16)(cacc[1][r] * linv);
  }
}

// ---------------------------------------------------------------------------
// Launcher. Workspace (halves), ~44 MB with aliasing (same layout as R7).
// ---------------------------------------------------------------------------
extern "C" void kernel_launch(void* const* d_in, const int* in_sizes, int n_in,
                              void* d_out, int out_size, void* d_ws, size_t ws_size,
                              hipStream_t stream)
{
  (void)in_sizes; (void)n_in; (void)out_size; (void)ws_size;
  const float* emb[4] = {(const float*)d_in[0], (const float*)d_in[1],
                         (const float*)d_in[2], (const float*)d_in[3]};
  const float* gamma1 = (const float*)d_in[18];
  const float* gamma2 = (const float*)d_in[20];
  float* out = (float*)d_out;

  h16* hws = (h16*)d_ws;
  h16* embC16 = hws;
  h16* QC16   = hws + 2359296L;
  h16* KC16   = hws + 4718592L;
  h16* VC16   = hws + 7077888L;
  h16* attnR  = hws + 9437184L;
  float* attnC = (float*)attnR;
  h16* WcT  = hws + 17825792L;
  h16* WkvT = WcT + 3145728L;
  h16* WqT  = WkvT + 131072L;
  h16* WoT  = WqT + 262144L;
  float* stats = (float*)(hws + 21626880L);
  float* sums = stats;
  float* Gk   = stats + 8;
  float* km   = Gk + 32768;
  float* Gq   = km + 1024;
  float* qm   = Gq + 131072;
  float* sc2v = qm + 4096;
  // aliases (lifetimes verified against launch order)
  h16* sim16  = QC16;
  h16* KVS16  = embC16;
  h16* Kbuf16 = attnR;
  h16* Vbuf16 = attnR + 2359296L;
  h16* Qbuf16 = attnR + 4718592L;
  h16* vT     = embC16;     // after KV-proj consumes KVS16
  h16* ctx16  = VC16;

  // zero sums + Gk + km (gram2 K-side accumulates via atomics)
  hipMemsetAsync(sums, 0, (8 + 32768 + 1024) * sizeof(float), stream);

  {
    WtP wp;
    wp.src[0] = (const float*)d_in[5];  wp.dst[0] = WcT;                 // WqC
    wp.src[1] = (const float*)d_in[6];  wp.dst[1] = WcT + 1048576L;      // WkC
    wp.src[2] = (const float*)d_in[7];  wp.dst[2] = WcT + 2097152L;      // WvC
    wp.src[3] = (const float*)d_in[12]; wp.dst[3] = WkvT;                // Wk
    wp.src[4] = (const float*)d_in[13]; wp.dst[4] = WkvT + 65536L;       // Wv
    for (int i = 0; i < 4; ++i) {
      wp.src[5 + i] = (const float*)d_in[8 + i];  wp.dst[5 + i] = WqT + (long)i * 65536;
      wp.src[9 + i] = (const float*)d_in[14 + i]; wp.dst[9 + i] = WoT + (long)i * 65536;
    }
    wp.embC = (const float*)d_in[4]; wp.dEmbC = embC16;
    wtrans<<<3232, 256, 0, stream>>>(wp);
  }

  // Stage A: [QC|KC|VC]16 = embC16 @ Wc  (2304 x 3072 x 1024), BM=64
  {
    GemmP gp{};
    gp.A[0] = embC16; gp.B[0] = WcT;
    gp.O[0][0] = QC16; gp.O[0][1] = KC16; gp.O[0][2] = VC16;
    mg<64,0,1,0,1,0,0,10><<<dim3(24,36,1), 256, 0, stream>>>(gp, 1024, 1024, 1024, 1024, nullptr);
  }
  // attn_c[b] = QC^T @ KC (1024x1024x576) fp32 + fused stats, BM=64
  {
    GemmP gp{};
    for (int z = 0; z < 4; ++z) {
      gp.A[z] = QC16 + (long)z * 589824; gp.B[z] = KC16 + (long)z * 589824;
      gp.O[z][0] = attnC + (long)z * CCl;
    }
    mg<64,1,0,0,0,0,1,30><<<dim3(8,16,4), 256, 0, stream>>>(gp, 576, 1024, 1024, 1024, sums);
  }
  softmax_c<<<4096, 256, 0, stream>>>(attnC, sums, gamma1, sim16);
  // T_hat[b] = VC @ sim^T -> KV_S layout fp16 (576x1024x1024)
  {
    GemmP gp{};
    for (int z = 0; z < 4; ++z) {
      gp.A[z] = VC16 + (long)z * 589824; gp.B[z] = sim16 + (long)z * CCl;
      gp.O[z][0] = KVS16 + (long)z * 589824;
    }
    mg<64,0,1,0,1,1,0,30><<<dim3(8,9,4), 256, 0, stream>>>(gp, 1024, 1024, 1024, 256, nullptr);
  }
  // K/V projections: (9216 x 512 x 256), BM=64
  {
    GemmP gp{};
    gp.A[0] = KVS16; gp.B[0] = WkvT;
    gp.O[0][0] = Kbuf16; gp.O[0][1] = Vbuf16;
    mg<64,0,1,0,1,0,0,8><<<dim3(4,144,1), 256, 0, stream>>>(gp, 256, 256, 256, 256, nullptr);
  }
  // Q projections: 4 x (2304 x 256 x 256), A fp32
  {
    GemmP gp{};
    for (int z = 0; z < 4; ++z) {
      gp.A32[z] = emb[z]; gp.B[z] = WqT + (long)z * 65536;
      gp.O[z][0] = Qbuf16 + (long)z * 589824;
    }
    mg<64,0,1,1,1,0,0,30><<<dim3(2,36,4), 256, 0, stream>>>(gp, 256, 256, 256, 256, nullptr);
  }
  // V pre-transpose for flash (KVS16 dead -> vT aliases it)
  vtrans<<<dim3(36,32), 256, 0, stream>>>(Vbuf16, vT);
  // analytic inorm scales for stage-2 attention (MFMA gram)
  gram2<<<192, 256, 0, stream>>>(Kbuf16, Qbuf16, Gk, km, Gq, qm);
  finalize_scale2<<<128, 256, 0, stream>>>(Gq, Gk, qm, km, gamma2, sc2v);
  // fold scale into Q (exp2 domain), then flash
  qscale<<<1152, 256, 0, stream>>>(Qbuf16, sc2v);
  flash6<<<1152, 256, 0, stream>>>(Qbuf16, Kbuf16, vT, ctx16);
  // output projections: 4 x (2304 x 256 x 256) -> fp32 d_out
  {
    GemmP gp{};
    for (int z = 0; z < 4; ++z) {
      gp.A[z] = ctx16 + (long)z * 589824; gp.B[z] = WoT + (long)z * 65536;
      gp.O[z][0] = out + (long)z * 589824;
    }
    mg<64,0,1,0,0,0,0,30><<<dim3(2,36,4), 256, 0, stream>>>(gp, 256, 256, 256, 256, nullptr);
  }
}